// Round 5
// baseline (2702.862 us; speedup 1.0000x reference)
//
#include <hip/hip_runtime.h>

#define NN 100000
#define NE 1600000
#define DD 128
#define HH 32
#define NB 196        // dst buckets of 512 nodes
#define SB 256        // scatter blocks
#define EPB 6250      // edges per scatter block (SB*EPB == NE)
#define BCAP 12288    // bucket capacity for LDS stage
#define QS 25000      // src quadrant size (sub-order within rows for L2 locality)
#define LB 1000       // persistent layer-kernel blocks (<=1024 co-resident by construction)
#define NPB 100       // nodes per block (LB*NPB == NN)

// ---- workspace layout (bytes) ----
#define OFF_P        0UL
#define OFF_BAR      12800000UL   // barrier state (cnt at +0, gen at +128)
#define OFF_PK       25600000UL
#define OFF_QOFF     32000000UL   // (4*NN+1) ints
#define OFF_COUNTS   33600128UL
#define OFF_POFS     33800832UL
#define OFF_BTOT     34001536UL
#define OFF_BBASE    34002560UL
#define OFF_STATS    34003584UL
#define OFF_W1T      34019968UL
#define OFF_W2T      34036352UL
#define OFF_MT       34052736UL
#define OFF_C        34065024UL
#define OFF_W3T      34065536UL

__device__ __forceinline__ int src_quad(int s) {
    return (s >= 2 * QS) ? ((s >= 3 * QS) ? 3 : 2) : ((s >= QS) ? 1 : 0);
}

// lock-free grid barrier: generation-based, device-scope atomics.
// Safe for reuse; initial gen value irrelevant; cnt zeroed by k_init each launch.
__device__ __forceinline__ void gbar(int* bar) {
    __threadfence();
    __syncthreads();
    if (threadIdx.x == 0) {
        int* cnt = bar;
        int* gen = bar + 32;
        int g = __hip_atomic_load(gen, __ATOMIC_RELAXED, __HIP_MEMORY_SCOPE_AGENT);
        int a = __hip_atomic_fetch_add(cnt, 1, __ATOMIC_ACQ_REL, __HIP_MEMORY_SCOPE_AGENT);
        if (a == LB - 1) {
            __hip_atomic_store(cnt, 0, __ATOMIC_RELAXED, __HIP_MEMORY_SCOPE_AGENT);
            __hip_atomic_store(gen, g + 1, __ATOMIC_RELEASE, __HIP_MEMORY_SCOPE_AGENT);
        } else {
            while (__hip_atomic_load(gen, __ATOMIC_ACQUIRE, __HIP_MEMORY_SCOPE_AGENT) == g)
                __builtin_amdgcn_s_sleep(2);
        }
    }
    __syncthreads();
}

// ---------- merged: binning count (blocks 0..255) + weight prep (256..271) ----------
__global__ void __launch_bounds__(256) k_init(const int* __restrict__ ei,
                                              int* __restrict__ counts,
                                              const float* __restrict__ W1,
                                              const float* __restrict__ W2,
                                              const float* __restrict__ W3,
                                              const float* __restrict__ b3,
                                              float* __restrict__ W1T,
                                              float* __restrict__ W2T,
                                              float* __restrict__ MT,
                                              float* __restrict__ C,
                                              float* __restrict__ W3T,
                                              int* __restrict__ bar) {
    int t = threadIdx.x;
    if (blockIdx.x < SB) {
        __shared__ int c[NB];
        if (t < NB) c[t] = 0;
        __syncthreads();
        int s = blockIdx.x * EPB;
        for (int e = s + t; e < s + EPB; e += 256)
            atomicAdd(&c[ei[NE + e] >> 9], 1);
        __syncthreads();
        if (t < NB) counts[t * SB + blockIdx.x] = c[t];
        return;
    }
    int b = blockIdx.x - SB;
    if (b < 12) {
        int d = b * 256 + t;                 // 0..3071
        int l = d >> 10, rem = d & 1023;
        int i = rem >> 5, j = rem & 31;
        const float* w1r = W1 + (l + 1) * HH * DD + i * DD;
        const float* w3c = W3 + l * DD * HH + j;
        float m = 0.f;
#pragma unroll 8
        for (int k = 0; k < DD; k++) m += w1r[k] * w3c[k * HH];
        MT[l * 1024 + j * 32 + i] = m;
    } else if (b == 12) {
        for (int idx = t; idx < 4096; idx += 256) {
            int jj = idx >> 7, kk = idx & 127;
            W1T[kk * 32 + jj] = W1[jj * 128 + kk];
        }
    } else if (b == 13) {
        for (int idx = t; idx < 4096; idx += 256) {
            int l = idx >> 10, rem = idx & 1023;
            int i = rem >> 5, j = rem & 31;
            W2T[l * 1024 + j * 32 + i] = W2[l * 1024 + i * 32 + j];
        }
    } else if (b == 14) {
        for (int idx = t; idx < 4096; idx += 256) {
            int jj = idx >> 5, kk = idx & 31;
            W3T[kk * 128 + jj] = W3[3 * 4096 + jj * 32 + kk];
        }
    } else {
        if (t < 96) {
            int l = t >> 5, ii = t & 31;
            const float* w1r = W1 + (l + 1) * HH * DD + ii * DD;
            const float* bb = b3 + l * DD;
            float c = 0.f;
#pragma unroll 8
            for (int k = 0; k < DD; k++) c += w1r[k] * bb[k];
            C[l * 32 + ii] = c;
        } else if (t == 128) {
            bar[0] = 0;   // barrier arrival counter (workspace is poisoned between runs)
        }
    }
}

__global__ void __launch_bounds__(256) k_scanX(const int* __restrict__ counts,
                                               int* __restrict__ pofs,
                                               int* __restrict__ btot) {
    __shared__ int s[256];
    int t = threadIdx.x, b = blockIdx.x;
    int v = counts[b * SB + t];
    s[t] = v;
    __syncthreads();
    for (int off = 1; off < 256; off <<= 1) {
        int x = (t >= off) ? s[t - off] : 0;
        __syncthreads();
        s[t] += x;
        __syncthreads();
    }
    pofs[b * SB + t] = s[t] - v;
    if (t == 255) btot[b] = s[255];
}

__global__ void __launch_bounds__(256) k_scanY(const int* __restrict__ btot,
                                               int* __restrict__ bbase,
                                               int* __restrict__ qoff) {
    __shared__ int s[256];
    int t = threadIdx.x;
    int v = (t < NB) ? btot[t] : 0;
    s[t] = v;
    __syncthreads();
    for (int off = 1; off < 256; off <<= 1) {
        int x = (t >= off) ? s[t - off] : 0;
        __syncthreads();
        s[t] += x;
        __syncthreads();
    }
    if (t < NB) bbase[t] = s[t] - v;
    if (t == NB - 1) bbase[NB] = s[t];
    if (t == 0) qoff[4 * NN] = NE;
}

__global__ void __launch_bounds__(256) k_scatter(const int* __restrict__ ei,
                                                 const int* __restrict__ pofs,
                                                 const int* __restrict__ bbase,
                                                 int* __restrict__ pk) {
    __shared__ int cur[NB];
    int t = threadIdx.x, blk = blockIdx.x;
    if (t < NB) cur[t] = bbase[t] + pofs[t * SB + blk];
    __syncthreads();
    int s = blk * EPB;
    for (int e = s + t; e < s + EPB; e += 256) {
        int src = ei[e], dst = ei[NE + e];
        int b = dst >> 9;
        int pos = atomicAdd(&cur[b], 1);
        pk[pos] = (src << 9) | (dst & 511);
    }
}

// ---------- bucket sort: key = (dst&511)*4 + src_quadrant; emits qoff CSR ----------
__global__ void __launch_bounds__(256) k_bucket(int* pk,
                                                const int* __restrict__ bbase,
                                                int* __restrict__ qoff) {
    __shared__ int cnt[2048];
    __shared__ int ts[256];
    __shared__ int stage[BCAP];
    int t = threadIdx.x, b = blockIdx.x;
    int base = bbase[b], end = bbase[b + 1];
#pragma unroll
    for (int j = 0; j < 8; j++) cnt[t * 8 + j] = 0;
    __syncthreads();
    for (int e = base + t; e < end; e += 256) {
        int v = pk[e];
        atomicAdd(&cnt[((v & 511) << 2) | src_quad(v >> 9)], 1);
    }
    __syncthreads();
    int c8[8];
    int p = 0;
#pragma unroll
    for (int j = 0; j < 8; j++) { c8[j] = cnt[t * 8 + j]; p += c8[j]; }
    ts[t] = p;
    __syncthreads();
    for (int off = 1; off < 256; off <<= 1) {
        int x = (t >= off) ? ts[t - off] : 0;
        __syncthreads();
        ts[t] += x;
        __syncthreads();
    }
    int run = ts[t] - p;
#pragma unroll
    for (int j = 0; j < 8; j++) {
        int ci = t * 8 + j;
        cnt[ci] = run;
        int n0 = b * 512 + (ci >> 2);
        if (n0 < NN) qoff[n0 * 4 + (ci & 3)] = base + run;
        run += c8[j];
    }
    __syncthreads();
    for (int e = base + t; e < end; e += 256) {
        int v = pk[e];
        int src = v >> 9;
        int pos = atomicAdd(&cnt[((v & 511) << 2) | src_quad(src)], 1);
        stage[pos] = src;
    }
    __syncthreads();
    int sz = end - base;
    for (int i = t; i < sz; i += 256) pk[base + i] = stage[i];
}

// ---------- P = X @ W1[0]^T : register-blocked, 128 nodes/block, grid 782 ----------
__global__ void __launch_bounds__(256) k_P(const float4* __restrict__ X4,
                                           const float4* __restrict__ W1T4,
                                           float4* __restrict__ P4) {
    __shared__ float xs[128 * 33];
    int t = threadIdx.x, blk = blockIdx.x;
    int i = t & 7, g = t >> 3;
    int nbase = blk * 128;
    float4 acc[4];
#pragma unroll
    for (int j = 0; j < 4; j++) acc[j] = make_float4(0.f, 0.f, 0.f, 0.f);
    for (int kt = 0; kt < 4; kt++) {
        __syncthreads();
#pragma unroll
        for (int q = 0; q < 4; q++) {
            int idx = t + 256 * q;
            int nd = idx >> 3, c4 = idx & 7;
            int node = nbase + nd;
            if (node > NN - 1) node = NN - 1;
            float4 v = X4[(size_t)node * 32 + kt * 8 + c4];
            float* dst = xs + nd * 33 + 4 * c4;
            dst[0] = v.x; dst[1] = v.y; dst[2] = v.z; dst[3] = v.w;
        }
        __syncthreads();
        const float4* Wk = W1T4 + (size_t)(kt * 32) * 8 + i;
        const float* xr0 = xs + (g * 4) * 33;
#pragma unroll
        for (int k = 0; k < 32; k++) {
            float4 w = Wk[k * 8];
            float x0 = xr0[k], x1 = xr0[33 + k], x2 = xr0[66 + k], x3 = xr0[99 + k];
            acc[0].x += x0 * w.x; acc[0].y += x0 * w.y; acc[0].z += x0 * w.z; acc[0].w += x0 * w.w;
            acc[1].x += x1 * w.x; acc[1].y += x1 * w.y; acc[1].z += x1 * w.z; acc[1].w += x1 * w.w;
            acc[2].x += x2 * w.x; acc[2].y += x2 * w.y; acc[2].z += x2 * w.z; acc[2].w += x2 * w.w;
            acc[3].x += x3 * w.x; acc[3].y += x3 * w.y; acc[3].z += x3 * w.z; acc[3].w += x3 * w.w;
        }
    }
    int node = nbase + g * 4;
#pragma unroll
    for (int j = 0; j < 4; j++)
        if (node + j < NN) P4[(size_t)(node + j) * 8 + i] = acc[j];
}

// ---------- persistent 4-layer kernel: A |b| D |b| F (|b| next layer) ----------
// LB=1000 x 256; NPB=100 nodes/block. launch_bounds(256,4) caps VGPR at 128 ->
// 4 blocks/CU; LDS 27.4KB -> 5/CU. 1000 <= 1024 co-resident guaranteed.
__global__ void __launch_bounds__(256, 4)
k_layers(float4* __restrict__ P4,
         const int* __restrict__ csr,
         const int* __restrict__ qoff,
         const float* __restrict__ eps,
         const float* __restrict__ b1,
         const float* __restrict__ g1,
         const float* __restrict__ bt1,
         const float* __restrict__ W2T,
         const float* __restrict__ b2,
         const float* __restrict__ g2,
         const float* __restrict__ bt2,
         const float* __restrict__ MT,
         const float* __restrict__ Cc,
         const float* __restrict__ W3T,
         const float* __restrict__ b3,
         float* __restrict__ gsAll,
         int* __restrict__ bar,
         float4* __restrict__ out4) {
    __shared__ float t1s[NPB * 33];
    __shared__ float t2s[NPB * 33];
    __shared__ float ls1[64], ls2[64];
    __shared__ float sc1[32], sh1[32], sc2[32], sh2[32];

    int t = threadIdx.x, bid = blockIdx.x;
    int g = t >> 3, i = t & 7;
    int nbase = bid * NPB;

    for (int l = 0; l < 4; l++) {
        float* gs1 = gsAll + l * 1024;
        float* gs2 = gs1 + 512;
        if (t < 64) { ls1[t] = 0.f; ls2[t] = 0.f; }
        __syncthreads();

        // ===== Phase A: aggregate + t1 -> LDS; BN1 stats =====
        {
            float e1 = 1.f + eps[l];
            float4 bb = ((const float4*)(b1 + l * 32))[i];
            float sx = 0.f, sy = 0.f, sz = 0.f, sw = 0.f;
            float qx = 0.f, qy = 0.f, qz = 0.f, qw = 0.f;
            for (int it = 0; it < 4; it++) {
                int nn = g + 32 * it;
                if (nn >= NPB) break;
                int n = nbase + nn;
                int e = qoff[4 * n], eend = qoff[4 * n + 4];
                float4 p = P4[(size_t)n * 8 + i];
                float4 acc;
                acc.x = e1 * p.x; acc.y = e1 * p.y; acc.z = e1 * p.z; acc.w = e1 * p.w;
                for (; e + 8 <= eend; e += 8) {
                    int s0 = csr[e], s1 = csr[e + 1], s2 = csr[e + 2], s3 = csr[e + 3];
                    int s4 = csr[e + 4], s5 = csr[e + 5], s6 = csr[e + 6], s7 = csr[e + 7];
                    float4 q0 = P4[(size_t)s0 * 8 + i];
                    float4 q1 = P4[(size_t)s1 * 8 + i];
                    float4 q2 = P4[(size_t)s2 * 8 + i];
                    float4 q3 = P4[(size_t)s3 * 8 + i];
                    float4 q4 = P4[(size_t)s4 * 8 + i];
                    float4 q5 = P4[(size_t)s5 * 8 + i];
                    float4 q6 = P4[(size_t)s6 * 8 + i];
                    float4 q7 = P4[(size_t)s7 * 8 + i];
                    acc.x += ((q0.x + q1.x) + (q2.x + q3.x)) + ((q4.x + q5.x) + (q6.x + q7.x));
                    acc.y += ((q0.y + q1.y) + (q2.y + q3.y)) + ((q4.y + q5.y) + (q6.y + q7.y));
                    acc.z += ((q0.z + q1.z) + (q2.z + q3.z)) + ((q4.z + q5.z) + (q6.z + q7.z));
                    acc.w += ((q0.w + q1.w) + (q2.w + q3.w)) + ((q4.w + q5.w) + (q6.w + q7.w));
                }
                for (; e + 4 <= eend; e += 4) {
                    int s0 = csr[e], s1 = csr[e + 1], s2 = csr[e + 2], s3 = csr[e + 3];
                    float4 q0 = P4[(size_t)s0 * 8 + i];
                    float4 q1 = P4[(size_t)s1 * 8 + i];
                    float4 q2 = P4[(size_t)s2 * 8 + i];
                    float4 q3 = P4[(size_t)s3 * 8 + i];
                    acc.x += (q0.x + q1.x) + (q2.x + q3.x);
                    acc.y += (q0.y + q1.y) + (q2.y + q3.y);
                    acc.z += (q0.z + q1.z) + (q2.z + q3.z);
                    acc.w += (q0.w + q1.w) + (q2.w + q3.w);
                }
                for (; e < eend; e++) {
                    int s = csr[e];
                    float4 q = P4[(size_t)s * 8 + i];
                    acc.x += q.x; acc.y += q.y; acc.z += q.z; acc.w += q.w;
                }
                acc.x += bb.x; acc.y += bb.y; acc.z += bb.z; acc.w += bb.w;
                float* dst = t1s + nn * 33 + 4 * i;
                dst[0] = acc.x; dst[1] = acc.y; dst[2] = acc.z; dst[3] = acc.w;
                sx += acc.x; sy += acc.y; sz += acc.z; sw += acc.w;
                qx += acc.x * acc.x; qy += acc.y * acc.y;
                qz += acc.z * acc.z; qw += acc.w * acc.w;
            }
#pragma unroll
            for (int off = 8; off < 64; off <<= 1) {
                sx += __shfl_xor(sx, off); sy += __shfl_xor(sy, off);
                sz += __shfl_xor(sz, off); sw += __shfl_xor(sw, off);
                qx += __shfl_xor(qx, off); qy += __shfl_xor(qy, off);
                qz += __shfl_xor(qz, off); qw += __shfl_xor(qw, off);
            }
            if ((t & 56) == 0) {
                atomicAdd(&ls1[4 * i + 0], sx); atomicAdd(&ls1[4 * i + 1], sy);
                atomicAdd(&ls1[4 * i + 2], sz); atomicAdd(&ls1[4 * i + 3], sw);
                atomicAdd(&ls1[32 + 4 * i + 0], qx); atomicAdd(&ls1[32 + 4 * i + 1], qy);
                atomicAdd(&ls1[32 + 4 * i + 2], qz); atomicAdd(&ls1[32 + 4 * i + 3], qw);
            }
            __syncthreads();
            if (t < 64) atomicAdd(&gs1[(bid & 7) * 64 + t], ls1[t]);
        }
        gbar(bar);

        // ===== Phase D: t2 = relu(bn1(t1)) @ W2^T + b2 -> LDS; BN2 stats =====
        {
            if (t < 32) {
                float s0 = 0.f, s1 = 0.f;
#pragma unroll
                for (int r = 0; r < 8; r++) { s0 += gs1[r * 64 + t]; s1 += gs1[r * 64 + 32 + t]; }
                float m = s0 * (1.f / NN);
                float var = s1 * (1.f / NN) - m * m;
                float s = g1[l * 32 + t] * rsqrtf(var + 1e-5f);
                sc1[t] = s; sh1[t] = bt1[l * 32 + t] - m * s;
            }
            __syncthreads();
            const float4* W2T4 = (const float4*)(W2T + l * 1024);
            float4 b2v = ((const float4*)(b2 + l * 32))[i];
            float sx = 0.f, sy = 0.f, sz = 0.f, sw = 0.f;
            float qx = 0.f, qy = 0.f, qz = 0.f, qw = 0.f;
            for (int it = 0; it < 4; it++) {
                int nn = g + 32 * it;
                if (nn >= NPB) break;
                float4 acc = b2v;
                const float* xr = t1s + nn * 33;
#pragma unroll
                for (int k = 0; k < 32; k++) {
                    float a = fmaxf(xr[k] * sc1[k] + sh1[k], 0.f);
                    float4 w = W2T4[k * 8 + i];
                    acc.x += a * w.x; acc.y += a * w.y; acc.z += a * w.z; acc.w += a * w.w;
                }
                float* dst = t2s + nn * 33 + 4 * i;
                dst[0] = acc.x; dst[1] = acc.y; dst[2] = acc.z; dst[3] = acc.w;
                sx += acc.x; sy += acc.y; sz += acc.z; sw += acc.w;
                qx += acc.x * acc.x; qy += acc.y * acc.y;
                qz += acc.z * acc.z; qw += acc.w * acc.w;
            }
#pragma unroll
            for (int off = 8; off < 64; off <<= 1) {
                sx += __shfl_xor(sx, off); sy += __shfl_xor(sy, off);
                sz += __shfl_xor(sz, off); sw += __shfl_xor(sw, off);
                qx += __shfl_xor(qx, off); qy += __shfl_xor(qy, off);
                qz += __shfl_xor(qz, off); qw += __shfl_xor(qw, off);
            }
            if ((t & 56) == 0) {
                atomicAdd(&ls2[4 * i + 0], sx); atomicAdd(&ls2[4 * i + 1], sy);
                atomicAdd(&ls2[4 * i + 2], sz); atomicAdd(&ls2[4 * i + 3], sw);
                atomicAdd(&ls2[32 + 4 * i + 0], qx); atomicAdd(&ls2[32 + 4 * i + 1], qy);
                atomicAdd(&ls2[32 + 4 * i + 2], qz); atomicAdd(&ls2[32 + 4 * i + 3], qw);
            }
            __syncthreads();
            if (t < 64) atomicAdd(&gs2[(bid & 7) * 64 + t], ls2[t]);
        }
        gbar(bar);

        // ===== Phase F =====
        if (t < 32) {
            float s0 = 0.f, s1 = 0.f;
#pragma unroll
            for (int r = 0; r < 8; r++) { s0 += gs2[r * 64 + t]; s1 += gs2[r * 64 + 32 + t]; }
            float m = s0 * (1.f / NN);
            float var = s1 * (1.f / NN) - m * m;
            float s = g2[l * 32 + t] * rsqrtf(var + 1e-5f);
            sc2[t] = s; sh2[t] = bt2[l * 32 + t] - m * s;
        }
        __syncthreads();
        if (l < 3) {
            const float4* Mt = (const float4*)MT + l * 256;
            float4 c0 = ((const float4*)(Cc + l * 32))[i];
            for (int it = 0; it < 4; it++) {
                int nn = g + 32 * it;
                if (nn >= NPB) break;
                int n = nbase + nn;
                float4 acc = c0;
                const float* xr = t2s + nn * 33;
#pragma unroll
                for (int k = 0; k < 32; k++) {
                    float a = fmaxf(xr[k] * sc2[k] + sh2[k], 0.f);
                    float4 w = Mt[k * 8 + i];
                    acc.x += a * w.x; acc.y += a * w.y; acc.z += a * w.z; acc.w += a * w.w;
                }
                P4[(size_t)n * 8 + i] = acc;
            }
            gbar(bar);   // next layer's gather reads P
        } else {
            int j = t & 31, gg = t >> 5;
            const float4* W3T4 = (const float4*)W3T;
            float4 b3v = ((const float4*)(b3 + 3 * 128))[j];
            for (int nn = gg; nn < NPB; nn += 8) {
                int n = nbase + nn;
                float4 acc = b3v;
                const float* xr = t2s + nn * 33;
#pragma unroll
                for (int k = 0; k < 32; k++) {
                    float a = fmaxf(xr[k] * sc2[k] + sh2[k], 0.f);
                    float4 w = W3T4[k * 32 + j];
                    acc.x += a * w.x; acc.y += a * w.y; acc.z += a * w.z; acc.w += a * w.w;
                }
                out4[(size_t)n * 32 + j] = acc;
            }
        }
    }
}

extern "C" void kernel_launch(void* const* d_in, const int* in_sizes, int n_in,
                              void* d_out, int out_size, void* d_ws, size_t ws_size,
                              hipStream_t stream) {
    const float* X   = (const float*)d_in[0];
    const int*   EI  = (const int*)d_in[1];
    const float* eps = (const float*)d_in[2];
    const float* W1  = (const float*)d_in[3];
    const float* b1  = (const float*)d_in[4];
    const float* g1  = (const float*)d_in[5];
    const float* bt1 = (const float*)d_in[6];
    const float* W2  = (const float*)d_in[7];
    const float* b2  = (const float*)d_in[8];
    const float* g2  = (const float*)d_in[9];
    const float* bt2 = (const float*)d_in[10];
    const float* W3  = (const float*)d_in[11];
    const float* b3  = (const float*)d_in[12];

    char* ws = (char*)d_ws;
    float* P       = (float*)(ws + OFF_P);
    int*   bar     = (int*)(ws + OFF_BAR);
    int*   pk      = (int*)(ws + OFF_PK);
    int*   qoff    = (int*)(ws + OFF_QOFF);
    int*   counts  = (int*)(ws + OFF_COUNTS);
    int*   pofs    = (int*)(ws + OFF_POFS);
    int*   btot    = (int*)(ws + OFF_BTOT);
    int*   bbase   = (int*)(ws + OFF_BBASE);
    float* stats   = (float*)(ws + OFF_STATS);
    float* W1T     = (float*)(ws + OFF_W1T);
    float* W2T     = (float*)(ws + OFF_W2T);
    float* MT      = (float*)(ws + OFF_MT);
    float* C       = (float*)(ws + OFF_C);
    float* W3T     = (float*)(ws + OFF_W3T);

    hipMemsetAsync(ws + OFF_STATS, 0, 16384, stream);

    k_init<<<SB + 16, 256, 0, stream>>>(EI, counts, W1, W2, W3, b3,
                                        W1T, W2T, MT, C, W3T, bar);
    k_scanX<<<NB, 256, 0, stream>>>(counts, pofs, btot);
    k_scanY<<<1, 256, 0, stream>>>(btot, bbase, qoff);
    k_scatter<<<SB, 256, 0, stream>>>(EI, pofs, bbase, pk);
    k_bucket<<<NB, 256, 0, stream>>>(pk, bbase, qoff);
    k_P<<<782, 256, 0, stream>>>((const float4*)X, (const float4*)W1T, (float4*)P);

    k_layers<<<LB, 256, 0, stream>>>((float4*)P, pk, qoff, eps, b1, g1, bt1,
                                     W2T, b2, g2, bt2, MT, C, W3T, b3,
                                     stats, bar, (float4*)d_out);
}

// Round 12
// 947.777 us; speedup vs baseline: 2.8518x; 2.8518x over previous
//
#include <hip/hip_runtime.h>

#define NN 100000
#define NE 1600000
#define DD 128
#define HH 32
#define NB 196        // dst buckets of 512 nodes
#define SB 256        // scatter blocks
#define EPB 6250      // edges per scatter block (SB*EPB == NE)
#define BCAP 12288    // bucket capacity for LDS stage
#define QS 25000      // src quadrant size (sub-order within rows for L2 locality)
#define LB 1000       // persistent layer-kernel blocks (<=1024 co-resident by construction)
#define NPB 100       // nodes per block (LB*NPB == NN)

// ---- workspace layout (bytes) ----
#define OFF_P        0UL
#define OFF_BAR      12800000UL   // barrier state (cnt at +0, gen at +128B)
#define OFF_PK       25600000UL
#define OFF_QOFF     32000000UL   // (4*NN+1) ints
#define OFF_COUNTS   33600128UL
#define OFF_POFS     33800832UL
#define OFF_BTOT     34001536UL
#define OFF_BBASE    34002560UL
#define OFF_STATS    34003584UL
#define OFF_W1T      34019968UL
#define OFF_W2T      34036352UL
#define OFF_MT       34052736UL
#define OFF_C        34065024UL
#define OFF_W3T      34065536UL

__device__ __forceinline__ int src_quad(int s) {
    return (s >= 2 * QS) ? ((s >= 3 * QS) ? 3 : 2) : ((s >= QS) ? 1 : 0);
}

// Grid barrier with ONE-SHOT fences (round-5 lesson: agent-scope ACQUIRE in the
// spin loop emits buffer_inv per poll -> continuous device-wide L2 invalidation,
// FETCH x4, 5.5x slowdown). Protocol:
//   arrivals: RELEASE fetch_add (one wbl2 writeback, no inv)
//   spin:     RELAXED load (agent-scope -> sc1 flag -> reads coherence point; no
//             cache-maintenance per poll, never stale -> live across XCDs)
//   wake/win: ONE acquire fence (single buffer_inv, exactly when needed)
__device__ __forceinline__ void gbar(int* bar) {
    __syncthreads();
    if (threadIdx.x == 0) {
        int* cnt = bar;
        int* gen = bar + 32;   // +128 B: separate cacheline from cnt
        int g = __hip_atomic_load(gen, __ATOMIC_RELAXED, __HIP_MEMORY_SCOPE_AGENT);
        int a = __hip_atomic_fetch_add(cnt, 1, __ATOMIC_RELEASE, __HIP_MEMORY_SCOPE_AGENT);
        if (a == LB - 1) {
            __builtin_amdgcn_fence(__ATOMIC_ACQUIRE, "agent");   // sync with all arrivals
            __hip_atomic_store(cnt, 0, __ATOMIC_RELAXED, __HIP_MEMORY_SCOPE_AGENT);
            __hip_atomic_store(gen, g + 1, __ATOMIC_RELEASE, __HIP_MEMORY_SCOPE_AGENT);
        } else {
            while (__hip_atomic_load(gen, __ATOMIC_RELAXED, __HIP_MEMORY_SCOPE_AGENT) == g)
                __builtin_amdgcn_s_sleep(8);
            __builtin_amdgcn_fence(__ATOMIC_ACQUIRE, "agent");   // one inv at wake
        }
    }
    __syncthreads();
}

// ---------- merged: binning count (blocks 0..255) + weight prep (256..271) ----------
__global__ void __launch_bounds__(256) k_init(const int* __restrict__ ei,
                                              int* __restrict__ counts,
                                              const float* __restrict__ W1,
                                              const float* __restrict__ W2,
                                              const float* __restrict__ W3,
                                              const float* __restrict__ b3,
                                              float* __restrict__ W1T,
                                              float* __restrict__ W2T,
                                              float* __restrict__ MT,
                                              float* __restrict__ C,
                                              float* __restrict__ W3T,
                                              int* __restrict__ bar) {
    int t = threadIdx.x;
    if (blockIdx.x < SB) {
        __shared__ int c[NB];
        if (t < NB) c[t] = 0;
        __syncthreads();
        int s = blockIdx.x * EPB;
        for (int e = s + t; e < s + EPB; e += 256)
            atomicAdd(&c[ei[NE + e] >> 9], 1);
        __syncthreads();
        if (t < NB) counts[t * SB + blockIdx.x] = c[t];
        return;
    }
    int b = blockIdx.x - SB;
    if (b < 12) {
        int d = b * 256 + t;                 // 0..3071
        int l = d >> 10, rem = d & 1023;
        int i = rem >> 5, j = rem & 31;
        const float* w1r = W1 + (l + 1) * HH * DD + i * DD;
        const float* w3c = W3 + l * DD * HH + j;
        float m = 0.f;
#pragma unroll 8
        for (int k = 0; k < DD; k++) m += w1r[k] * w3c[k * HH];
        MT[l * 1024 + j * 32 + i] = m;
    } else if (b == 12) {
        for (int idx = t; idx < 4096; idx += 256) {
            int jj = idx >> 7, kk = idx & 127;
            W1T[kk * 32 + jj] = W1[jj * 128 + kk];
        }
    } else if (b == 13) {
        for (int idx = t; idx < 4096; idx += 256) {
            int l = idx >> 10, rem = idx & 1023;
            int i = rem >> 5, j = rem & 31;
            W2T[l * 1024 + j * 32 + i] = W2[l * 1024 + i * 32 + j];
        }
    } else if (b == 14) {
        for (int idx = t; idx < 4096; idx += 256) {
            int jj = idx >> 5, kk = idx & 31;
            W3T[kk * 128 + jj] = W3[3 * 4096 + jj * 32 + kk];
        }
    } else {
        if (t < 96) {
            int l = t >> 5, ii = t & 31;
            const float* w1r = W1 + (l + 1) * HH * DD + ii * DD;
            const float* bb = b3 + l * DD;
            float c = 0.f;
#pragma unroll 8
            for (int k = 0; k < DD; k++) c += w1r[k] * bb[k];
            C[l * 32 + ii] = c;
        } else if (t == 128) {
            bar[0] = 0;   // arrival counter (workspace is poisoned between runs; gen value irrelevant)
        }
    }
}

__global__ void __launch_bounds__(256) k_scanX(const int* __restrict__ counts,
                                               int* __restrict__ pofs,
                                               int* __restrict__ btot) {
    __shared__ int s[256];
    int t = threadIdx.x, b = blockIdx.x;
    int v = counts[b * SB + t];
    s[t] = v;
    __syncthreads();
    for (int off = 1; off < 256; off <<= 1) {
        int x = (t >= off) ? s[t - off] : 0;
        __syncthreads();
        s[t] += x;
        __syncthreads();
    }
    pofs[b * SB + t] = s[t] - v;
    if (t == 255) btot[b] = s[255];
}

__global__ void __launch_bounds__(256) k_scanY(const int* __restrict__ btot,
                                               int* __restrict__ bbase,
                                               int* __restrict__ qoff) {
    __shared__ int s[256];
    int t = threadIdx.x;
    int v = (t < NB) ? btot[t] : 0;
    s[t] = v;
    __syncthreads();
    for (int off = 1; off < 256; off <<= 1) {
        int x = (t >= off) ? s[t - off] : 0;
        __syncthreads();
        s[t] += x;
        __syncthreads();
    }
    if (t < NB) bbase[t] = s[t] - v;
    if (t == NB - 1) bbase[NB] = s[t];
    if (t == 0) qoff[4 * NN] = NE;
}

__global__ void __launch_bounds__(256) k_scatter(const int* __restrict__ ei,
                                                 const int* __restrict__ pofs,
                                                 const int* __restrict__ bbase,
                                                 int* __restrict__ pk) {
    __shared__ int cur[NB];
    int t = threadIdx.x, blk = blockIdx.x;
    if (t < NB) cur[t] = bbase[t] + pofs[t * SB + blk];
    __syncthreads();
    int s = blk * EPB;
    for (int e = s + t; e < s + EPB; e += 256) {
        int src = ei[e], dst = ei[NE + e];
        int b = dst >> 9;
        int pos = atomicAdd(&cur[b], 1);
        pk[pos] = (src << 9) | (dst & 511);
    }
}

// ---------- bucket sort: key = (dst&511)*4 + src_quadrant; emits qoff CSR ----------
__global__ void __launch_bounds__(256) k_bucket(int* pk,
                                                const int* __restrict__ bbase,
                                                int* __restrict__ qoff) {
    __shared__ int cnt[2048];
    __shared__ int ts[256];
    __shared__ int stage[BCAP];
    int t = threadIdx.x, b = blockIdx.x;
    int base = bbase[b], end = bbase[b + 1];
#pragma unroll
    for (int j = 0; j < 8; j++) cnt[t * 8 + j] = 0;
    __syncthreads();
    for (int e = base + t; e < end; e += 256) {
        int v = pk[e];
        atomicAdd(&cnt[((v & 511) << 2) | src_quad(v >> 9)], 1);
    }
    __syncthreads();
    int c8[8];
    int p = 0;
#pragma unroll
    for (int j = 0; j < 8; j++) { c8[j] = cnt[t * 8 + j]; p += c8[j]; }
    ts[t] = p;
    __syncthreads();
    for (int off = 1; off < 256; off <<= 1) {
        int x = (t >= off) ? ts[t - off] : 0;
        __syncthreads();
        ts[t] += x;
        __syncthreads();
    }
    int run = ts[t] - p;
#pragma unroll
    for (int j = 0; j < 8; j++) {
        int ci = t * 8 + j;
        cnt[ci] = run;
        int n0 = b * 512 + (ci >> 2);
        if (n0 < NN) qoff[n0 * 4 + (ci & 3)] = base + run;
        run += c8[j];
    }
    __syncthreads();
    for (int e = base + t; e < end; e += 256) {
        int v = pk[e];
        int src = v >> 9;
        int pos = atomicAdd(&cnt[((v & 511) << 2) | src_quad(src)], 1);
        stage[pos] = src;
    }
    __syncthreads();
    int sz = end - base;
    for (int i = t; i < sz; i += 256) pk[base + i] = stage[i];
}

// ---------- P = X @ W1[0]^T : register-blocked, 128 nodes/block, grid 782 ----------
__global__ void __launch_bounds__(256) k_P(const float4* __restrict__ X4,
                                           const float4* __restrict__ W1T4,
                                           float4* __restrict__ P4) {
    __shared__ float xs[128 * 33];
    int t = threadIdx.x, blk = blockIdx.x;
    int i = t & 7, g = t >> 3;
    int nbase = blk * 128;
    float4 acc[4];
#pragma unroll
    for (int j = 0; j < 4; j++) acc[j] = make_float4(0.f, 0.f, 0.f, 0.f);
    for (int kt = 0; kt < 4; kt++) {
        __syncthreads();
#pragma unroll
        for (int q = 0; q < 4; q++) {
            int idx = t + 256 * q;
            int nd = idx >> 3, c4 = idx & 7;
            int node = nbase + nd;
            if (node > NN - 1) node = NN - 1;
            float4 v = X4[(size_t)node * 32 + kt * 8 + c4];
            float* dst = xs + nd * 33 + 4 * c4;
            dst[0] = v.x; dst[1] = v.y; dst[2] = v.z; dst[3] = v.w;
        }
        __syncthreads();
        const float4* Wk = W1T4 + (size_t)(kt * 32) * 8 + i;
        const float* xr0 = xs + (g * 4) * 33;
#pragma unroll
        for (int k = 0; k < 32; k++) {
            float4 w = Wk[k * 8];
            float x0 = xr0[k], x1 = xr0[33 + k], x2 = xr0[66 + k], x3 = xr0[99 + k];
            acc[0].x += x0 * w.x; acc[0].y += x0 * w.y; acc[0].z += x0 * w.z; acc[0].w += x0 * w.w;
            acc[1].x += x1 * w.x; acc[1].y += x1 * w.y; acc[1].z += x1 * w.z; acc[1].w += x1 * w.w;
            acc[2].x += x2 * w.x; acc[2].y += x2 * w.y; acc[2].z += x2 * w.z; acc[2].w += x2 * w.w;
            acc[3].x += x3 * w.x; acc[3].y += x3 * w.y; acc[3].z += x3 * w.z; acc[3].w += x3 * w.w;
        }
    }
    int node = nbase + g * 4;
#pragma unroll
    for (int j = 0; j < 4; j++)
        if (node + j < NN) P4[(size_t)(node + j) * 8 + i] = acc[j];
}

// ---------- persistent 4-layer kernel: A |b| D |b| F (|b| next layer) ----------
// LB=1000 x 256; NPB=100 nodes/block. launch_bounds(256,4) caps VGPR at 128 ->
// 4 blocks/CU; LDS 27.4KB -> 5/CU. 1000 <= 1024 co-resident guaranteed.
__global__ void __launch_bounds__(256, 4)
k_layers(float4* __restrict__ P4,
         const int* __restrict__ csr,
         const int* __restrict__ qoff,
         const float* __restrict__ eps,
         const float* __restrict__ b1,
         const float* __restrict__ g1,
         const float* __restrict__ bt1,
         const float* __restrict__ W2T,
         const float* __restrict__ b2,
         const float* __restrict__ g2,
         const float* __restrict__ bt2,
         const float* __restrict__ MT,
         const float* __restrict__ Cc,
         const float* __restrict__ W3T,
         const float* __restrict__ b3,
         float* __restrict__ gsAll,
         int* __restrict__ bar,
         float4* __restrict__ out4) {
    __shared__ float t1s[NPB * 33];
    __shared__ float t2s[NPB * 33];
    __shared__ float ls1[64], ls2[64];
    __shared__ float sc1[32], sh1[32], sc2[32], sh2[32];

    int t = threadIdx.x, bid = blockIdx.x;
    int g = t >> 3, i = t & 7;
    int nbase = bid * NPB;

    for (int l = 0; l < 4; l++) {
        float* gs1 = gsAll + l * 1024;
        float* gs2 = gs1 + 512;
        if (t < 64) { ls1[t] = 0.f; ls2[t] = 0.f; }
        __syncthreads();

        // ===== Phase A: aggregate + t1 -> LDS; BN1 stats =====
        {
            float e1 = 1.f + eps[l];
            float4 bb = ((const float4*)(b1 + l * 32))[i];
            float sx = 0.f, sy = 0.f, sz = 0.f, sw = 0.f;
            float qx = 0.f, qy = 0.f, qz = 0.f, qw = 0.f;
            for (int it = 0; it < 4; it++) {
                int nn = g + 32 * it;
                if (nn >= NPB) break;
                int n = nbase + nn;
                int e = qoff[4 * n], eend = qoff[4 * n + 4];
                float4 p = P4[(size_t)n * 8 + i];
                float4 acc;
                acc.x = e1 * p.x; acc.y = e1 * p.y; acc.z = e1 * p.z; acc.w = e1 * p.w;
                for (; e + 8 <= eend; e += 8) {
                    int s0 = csr[e], s1 = csr[e + 1], s2 = csr[e + 2], s3 = csr[e + 3];
                    int s4 = csr[e + 4], s5 = csr[e + 5], s6 = csr[e + 6], s7 = csr[e + 7];
                    float4 q0 = P4[(size_t)s0 * 8 + i];
                    float4 q1 = P4[(size_t)s1 * 8 + i];
                    float4 q2 = P4[(size_t)s2 * 8 + i];
                    float4 q3 = P4[(size_t)s3 * 8 + i];
                    float4 q4 = P4[(size_t)s4 * 8 + i];
                    float4 q5 = P4[(size_t)s5 * 8 + i];
                    float4 q6 = P4[(size_t)s6 * 8 + i];
                    float4 q7 = P4[(size_t)s7 * 8 + i];
                    acc.x += ((q0.x + q1.x) + (q2.x + q3.x)) + ((q4.x + q5.x) + (q6.x + q7.x));
                    acc.y += ((q0.y + q1.y) + (q2.y + q3.y)) + ((q4.y + q5.y) + (q6.y + q7.y));
                    acc.z += ((q0.z + q1.z) + (q2.z + q3.z)) + ((q4.z + q5.z) + (q6.z + q7.z));
                    acc.w += ((q0.w + q1.w) + (q2.w + q3.w)) + ((q4.w + q5.w) + (q6.w + q7.w));
                }
                for (; e + 4 <= eend; e += 4) {
                    int s0 = csr[e], s1 = csr[e + 1], s2 = csr[e + 2], s3 = csr[e + 3];
                    float4 q0 = P4[(size_t)s0 * 8 + i];
                    float4 q1 = P4[(size_t)s1 * 8 + i];
                    float4 q2 = P4[(size_t)s2 * 8 + i];
                    float4 q3 = P4[(size_t)s3 * 8 + i];
                    acc.x += (q0.x + q1.x) + (q2.x + q3.x);
                    acc.y += (q0.y + q1.y) + (q2.y + q3.y);
                    acc.z += (q0.z + q1.z) + (q2.z + q3.z);
                    acc.w += (q0.w + q1.w) + (q2.w + q3.w);
                }
                for (; e < eend; e++) {
                    int s = csr[e];
                    float4 q = P4[(size_t)s * 8 + i];
                    acc.x += q.x; acc.y += q.y; acc.z += q.z; acc.w += q.w;
                }
                acc.x += bb.x; acc.y += bb.y; acc.z += bb.z; acc.w += bb.w;
                float* dst = t1s + nn * 33 + 4 * i;
                dst[0] = acc.x; dst[1] = acc.y; dst[2] = acc.z; dst[3] = acc.w;
                sx += acc.x; sy += acc.y; sz += acc.z; sw += acc.w;
                qx += acc.x * acc.x; qy += acc.y * acc.y;
                qz += acc.z * acc.z; qw += acc.w * acc.w;
            }
#pragma unroll
            for (int off = 8; off < 64; off <<= 1) {
                sx += __shfl_xor(sx, off); sy += __shfl_xor(sy, off);
                sz += __shfl_xor(sz, off); sw += __shfl_xor(sw, off);
                qx += __shfl_xor(qx, off); qy += __shfl_xor(qy, off);
                qz += __shfl_xor(qz, off); qw += __shfl_xor(qw, off);
            }
            if ((t & 56) == 0) {
                atomicAdd(&ls1[4 * i + 0], sx); atomicAdd(&ls1[4 * i + 1], sy);
                atomicAdd(&ls1[4 * i + 2], sz); atomicAdd(&ls1[4 * i + 3], sw);
                atomicAdd(&ls1[32 + 4 * i + 0], qx); atomicAdd(&ls1[32 + 4 * i + 1], qy);
                atomicAdd(&ls1[32 + 4 * i + 2], qz); atomicAdd(&ls1[32 + 4 * i + 3], qw);
            }
            __syncthreads();
            if (t < 64) atomicAdd(&gs1[(bid & 7) * 64 + t], ls1[t]);
        }
        gbar(bar);

        // ===== Phase D: t2 = relu(bn1(t1)) @ W2^T + b2 -> LDS; BN2 stats =====
        {
            if (t < 32) {
                float s0 = 0.f, s1 = 0.f;
#pragma unroll
                for (int r = 0; r < 8; r++) { s0 += gs1[r * 64 + t]; s1 += gs1[r * 64 + 32 + t]; }
                float m = s0 * (1.f / NN);
                float var = s1 * (1.f / NN) - m * m;
                float s = g1[l * 32 + t] * rsqrtf(var + 1e-5f);
                sc1[t] = s; sh1[t] = bt1[l * 32 + t] - m * s;
            }
            __syncthreads();
            const float4* W2T4 = (const float4*)(W2T + l * 1024);
            float4 b2v = ((const float4*)(b2 + l * 32))[i];
            float sx = 0.f, sy = 0.f, sz = 0.f, sw = 0.f;
            float qx = 0.f, qy = 0.f, qz = 0.f, qw = 0.f;
            for (int it = 0; it < 4; it++) {
                int nn = g + 32 * it;
                if (nn >= NPB) break;
                float4 acc = b2v;
                const float* xr = t1s + nn * 33;
#pragma unroll
                for (int k = 0; k < 32; k++) {
                    float a = fmaxf(xr[k] * sc1[k] + sh1[k], 0.f);
                    float4 w = W2T4[k * 8 + i];
                    acc.x += a * w.x; acc.y += a * w.y; acc.z += a * w.z; acc.w += a * w.w;
                }
                float* dst = t2s + nn * 33 + 4 * i;
                dst[0] = acc.x; dst[1] = acc.y; dst[2] = acc.z; dst[3] = acc.w;
                sx += acc.x; sy += acc.y; sz += acc.z; sw += acc.w;
                qx += acc.x * acc.x; qy += acc.y * acc.y;
                qz += acc.z * acc.z; qw += acc.w * acc.w;
            }
#pragma unroll
            for (int off = 8; off < 64; off <<= 1) {
                sx += __shfl_xor(sx, off); sy += __shfl_xor(sy, off);
                sz += __shfl_xor(sz, off); sw += __shfl_xor(sw, off);
                qx += __shfl_xor(qx, off); qy += __shfl_xor(qy, off);
                qz += __shfl_xor(qz, off); qw += __shfl_xor(qw, off);
            }
            if ((t & 56) == 0) {
                atomicAdd(&ls2[4 * i + 0], sx); atomicAdd(&ls2[4 * i + 1], sy);
                atomicAdd(&ls2[4 * i + 2], sz); atomicAdd(&ls2[4 * i + 3], sw);
                atomicAdd(&ls2[32 + 4 * i + 0], qx); atomicAdd(&ls2[32 + 4 * i + 1], qy);
                atomicAdd(&ls2[32 + 4 * i + 2], qz); atomicAdd(&ls2[32 + 4 * i + 3], qw);
            }
            __syncthreads();
            if (t < 64) atomicAdd(&gs2[(bid & 7) * 64 + t], ls2[t]);
        }
        gbar(bar);

        // ===== Phase F =====
        if (t < 32) {
            float s0 = 0.f, s1 = 0.f;
#pragma unroll
            for (int r = 0; r < 8; r++) { s0 += gs2[r * 64 + t]; s1 += gs2[r * 64 + 32 + t]; }
            float m = s0 * (1.f / NN);
            float var = s1 * (1.f / NN) - m * m;
            float s = g2[l * 32 + t] * rsqrtf(var + 1e-5f);
            sc2[t] = s; sh2[t] = bt2[l * 32 + t] - m * s;
        }
        __syncthreads();
        if (l < 3) {
            const float4* Mt = (const float4*)MT + l * 256;
            float4 c0 = ((const float4*)(Cc + l * 32))[i];
            for (int it = 0; it < 4; it++) {
                int nn = g + 32 * it;
                if (nn >= NPB) break;
                int n = nbase + nn;
                float4 acc = c0;
                const float* xr = t2s + nn * 33;
#pragma unroll
                for (int k = 0; k < 32; k++) {
                    float a = fmaxf(xr[k] * sc2[k] + sh2[k], 0.f);
                    float4 w = Mt[k * 8 + i];
                    acc.x += a * w.x; acc.y += a * w.y; acc.z += a * w.z; acc.w += a * w.w;
                }
                P4[(size_t)n * 8 + i] = acc;
            }
            gbar(bar);   // next layer's gather reads P
        } else {
            int j = t & 31, gg = t >> 5;
            const float4* W3T4 = (const float4*)W3T;
            float4 b3v = ((const float4*)(b3 + 3 * 128))[j];
            for (int nn = gg; nn < NPB; nn += 8) {
                int n = nbase + nn;
                float4 acc = b3v;
                const float* xr = t2s + nn * 33;
#pragma unroll
                for (int k = 0; k < 32; k++) {
                    float a = fmaxf(xr[k] * sc2[k] + sh2[k], 0.f);
                    float4 w = W3T4[k * 32 + j];
                    acc.x += a * w.x; acc.y += a * w.y; acc.z += a * w.z; acc.w += a * w.w;
                }
                out4[(size_t)n * 32 + j] = acc;
            }
        }
    }
}

extern "C" void kernel_launch(void* const* d_in, const int* in_sizes, int n_in,
                              void* d_out, int out_size, void* d_ws, size_t ws_size,
                              hipStream_t stream) {
    const float* X   = (const float*)d_in[0];
    const int*   EI  = (const int*)d_in[1];
    const float* eps = (const float*)d_in[2];
    const float* W1  = (const float*)d_in[3];
    const float* b1  = (const float*)d_in[4];
    const float* g1  = (const float*)d_in[5];
    const float* bt1 = (const float*)d_in[6];
    const float* W2  = (const float*)d_in[7];
    const float* b2  = (const float*)d_in[8];
    const float* g2  = (const float*)d_in[9];
    const float* bt2 = (const float*)d_in[10];
    const float* W3  = (const float*)d_in[11];
    const float* b3  = (const float*)d_in[12];

    char* ws = (char*)d_ws;
    float* P       = (float*)(ws + OFF_P);
    int*   bar     = (int*)(ws + OFF_BAR);
    int*   pk      = (int*)(ws + OFF_PK);
    int*   qoff    = (int*)(ws + OFF_QOFF);
    int*   counts  = (int*)(ws + OFF_COUNTS);
    int*   pofs    = (int*)(ws + OFF_POFS);
    int*   btot    = (int*)(ws + OFF_BTOT);
    int*   bbase   = (int*)(ws + OFF_BBASE);
    float* stats   = (float*)(ws + OFF_STATS);
    float* W1T     = (float*)(ws + OFF_W1T);
    float* W2T     = (float*)(ws + OFF_W2T);
    float* MT      = (float*)(ws + OFF_MT);
    float* C       = (float*)(ws + OFF_C);
    float* W3T     = (float*)(ws + OFF_W3T);

    hipMemsetAsync(ws + OFF_STATS, 0, 16384, stream);

    k_init<<<SB + 16, 256, 0, stream>>>(EI, counts, W1, W2, W3, b3,
                                        W1T, W2T, MT, C, W3T, bar);
    k_scanX<<<NB, 256, 0, stream>>>(counts, pofs, btot);
    k_scanY<<<1, 256, 0, stream>>>(btot, bbase, qoff);
    k_scatter<<<SB, 256, 0, stream>>>(EI, pofs, bbase, pk);
    k_bucket<<<NB, 256, 0, stream>>>(pk, bbase, qoff);
    k_P<<<782, 256, 0, stream>>>((const float4*)X, (const float4*)W1T, (float4*)P);

    k_layers<<<LB, 256, 0, stream>>>((float4*)P, pk, qoff, eps, b1, g1, bt1,
                                     W2T, b2, g2, bt2, MT, C, W3T, b3,
                                     stats, bar, (float4*)d_out);
}

// Round 15
// 478.613 us; speedup vs baseline: 5.6473x; 1.9803x over previous
//
#include <hip/hip_runtime.h>

#define NN 100000
#define NE 1600000
#define DD 128
#define HH 32
#define NB 196        // dst buckets of 512 nodes
#define SB 256        // scatter blocks
#define EPB 6250      // edges per scatter block (SB*EPB == NE)
#define BCAP 12288    // bucket capacity for LDS stage
#define QS 25000      // src quadrant size (sub-order within rows for L2 locality)

// ---- workspace layout (bytes) ----
#define OFF_P        0UL
#define OFF_T        12800000UL
#define OFF_PK       25600000UL
#define OFF_QOFF     32000000UL   // (4*NN+1) ints
#define OFF_COUNTS   33600128UL   // 256*256 ints (scatter-block-major)
#define OFF_STATS    34003584UL
#define OFF_W2T      34036352UL
#define OFF_MT       34052736UL
#define OFF_C        34065024UL
#define OFF_W3T      34065536UL

__device__ __forceinline__ int src_quad(int s) {
    return (s >= 2 * QS) ? ((s >= 3 * QS) ? 3 : 2) : ((s >= QS) ? 1 : 0);
}

// ---------- merged prologue: count (0..255) + weight prep (256..270) + k_P (271..1052) ----------
// counts layout: counts[scatter_block * 256 + bucket]  (coalesced write AND read)
__global__ void __launch_bounds__(256) k_init(const int* __restrict__ ei,
                                              int* __restrict__ counts,
                                              const float* __restrict__ W1,
                                              const float* __restrict__ W2,
                                              const float* __restrict__ W3,
                                              const float* __restrict__ b3,
                                              float* __restrict__ W2T,
                                              float* __restrict__ MT,
                                              float* __restrict__ C,
                                              float* __restrict__ W3T,
                                              float* __restrict__ stats,
                                              const float4* __restrict__ X4,
                                              float4* __restrict__ P4) {
    __shared__ __align__(16) char smem[33280];   // union: c[NB] | xs[128*33]f + ws[4096]f
    int t = threadIdx.x;
    if (blockIdx.x < SB) {
        int* c = (int*)smem;
        if (t < NB) c[t] = 0;
        __syncthreads();
        int s = blockIdx.x * EPB;
        for (int e = s + t; e < s + EPB; e += 256)
            atomicAdd(&c[ei[NE + e] >> 9], 1);
        __syncthreads();
        if (t < NB) counts[blockIdx.x * 256 + t] = c[t];
        return;
    }
    int b = blockIdx.x - SB;
    if (b < 12) {
        int d = b * 256 + t;                 // 0..3071
        int l = d >> 10, rem = d & 1023;
        int i = rem >> 5, j = rem & 31;
        const float* w1r = W1 + (l + 1) * HH * DD + i * DD;
        const float* w3c = W3 + l * DD * HH + j;
        float m = 0.f;
#pragma unroll 8
        for (int k = 0; k < DD; k++) m += w1r[k] * w3c[k * HH];
        MT[l * 1024 + j * 32 + i] = m;
        return;
    } else if (b == 12) {
        for (int idx = t; idx < 4096; idx += 256) {
            int l = idx >> 10, rem = idx & 1023;
            int i = rem >> 5, j = rem & 31;
            W2T[l * 1024 + j * 32 + i] = W2[l * 1024 + i * 32 + j];
        }
        return;
    } else if (b == 13) {
        for (int idx = t; idx < 4096; idx += 256) {
            int jj = idx >> 5, kk = idx & 31;
            W3T[kk * 128 + jj] = W3[3 * 4096 + jj * 32 + kk];
        }
        return;
    } else if (b == 14) {
        if (t < 96) {
            int l = t >> 5, ii = t & 31;
            const float* w1r = W1 + (l + 1) * HH * DD + ii * DD;
            const float* bb = b3 + l * DD;
            float c = 0.f;
#pragma unroll 8
            for (int k = 0; k < DD; k++) c += w1r[k] * bb[k];
            C[l * 32 + ii] = c;
        }
        for (int idx = t; idx < 4096; idx += 256) stats[idx] = 0.f;  // replaces memset
        return;
    }
    // ---- k_P: P = X @ W1[0]^T, self-contained (W1 transposed into LDS) ----
    int blk = b - 15;                        // 0..781
    float* xs = (float*)smem;                // [128*33]
    float* ws = (float*)(smem + 16896);      // [128][32] = W1^T, 16B-aligned
    for (int d = t; d < 4096; d += 256) {    // dst-ordered: LDS conflict-free
        int kk = d >> 5, jj = d & 31;
        ws[d] = W1[jj * 128 + kk];
    }
    const float4* ws4 = (const float4*)ws;
    int i = t & 7, g = t >> 3;
    int nbase = blk * 128;
    float4 acc[4];
#pragma unroll
    for (int j = 0; j < 4; j++) acc[j] = make_float4(0.f, 0.f, 0.f, 0.f);
    for (int kt = 0; kt < 4; kt++) {
        __syncthreads();
#pragma unroll
        for (int q = 0; q < 4; q++) {
            int idx = t + 256 * q;
            int nd = idx >> 3, c4 = idx & 7;
            int node = nbase + nd;
            if (node > NN - 1) node = NN - 1;
            float4 v = X4[(size_t)node * 32 + kt * 8 + c4];
            float* dst = xs + nd * 33 + 4 * c4;
            dst[0] = v.x; dst[1] = v.y; dst[2] = v.z; dst[3] = v.w;
        }
        __syncthreads();
        const float4* Wk = ws4 + (size_t)(kt * 32) * 8 + i;
        const float* xr0 = xs + (g * 4) * 33;
#pragma unroll
        for (int k = 0; k < 32; k++) {
            float4 w = Wk[k * 8];
            float x0 = xr0[k], x1 = xr0[33 + k], x2 = xr0[66 + k], x3 = xr0[99 + k];
            acc[0].x += x0 * w.x; acc[0].y += x0 * w.y; acc[0].z += x0 * w.z; acc[0].w += x0 * w.w;
            acc[1].x += x1 * w.x; acc[1].y += x1 * w.y; acc[1].z += x1 * w.z; acc[1].w += x1 * w.w;
            acc[2].x += x2 * w.x; acc[2].y += x2 * w.y; acc[2].z += x2 * w.z; acc[2].w += x2 * w.w;
            acc[3].x += x3 * w.x; acc[3].y += x3 * w.y; acc[3].z += x3 * w.z; acc[3].w += x3 * w.w;
        }
    }
    int node = nbase + g * 4;
#pragma unroll
    for (int j = 0; j < 4; j++)
        if (node + j < NN) P4[(size_t)(node + j) * 8 + i] = acc[j];
}

// ---------- scatter: recomputes its own pofs column + bbase from counts in-block ----------
__global__ void __launch_bounds__(256) k_scatter(const int* __restrict__ ei,
                                                 const int* __restrict__ counts,
                                                 int* __restrict__ pk) {
    __shared__ int ts[256];
    __shared__ int cur[NB];
    int t = threadIdx.x, blk = blockIdx.x;
    int partial = 0, total = 0;
    if (t < NB) {
        for (int j = 0; j < SB; j++) {
            int c = counts[j * 256 + t];     // coalesced across t
            total += c;
            if (j < blk) partial += c;
        }
    }
    ts[t] = (t < NB) ? total : 0;
    __syncthreads();
    for (int off = 1; off < 256; off <<= 1) {
        int x = (t >= off) ? ts[t - off] : 0;
        __syncthreads();
        ts[t] += x;
        __syncthreads();
    }
    if (t < NB) cur[t] = (ts[t] - total) + partial;   // bbase_excl + pofs
    __syncthreads();
    int s = blk * EPB;
    for (int e = s + t; e < s + EPB; e += 256) {
        int src = ei[e], dst = ei[NE + e];
        int b = dst >> 9;
        int pos = atomicAdd(&cur[b], 1);
        pk[pos] = (src << 9) | (dst & 511);
    }
}

// ---------- bucket sort: key = (dst&511)*4 + src_quadrant; emits qoff CSR ----------
__global__ void __launch_bounds__(256) k_bucket(int* pk,
                                                const int* __restrict__ counts,
                                                int* __restrict__ qoff) {
    __shared__ int cnt[2048];
    __shared__ int ts[256];
    __shared__ int stage[BCAP];
    int t = threadIdx.x, b = blockIdx.x;
    // in-block bbase: total per bucket + scan
    int total = 0;
    if (t < NB) {
        for (int j = 0; j < SB; j++) total += counts[j * 256 + t];
    }
    ts[t] = (t < NB) ? total : 0;
    __syncthreads();
    for (int off = 1; off < 256; off <<= 1) {
        int x = (t >= off) ? ts[t - off] : 0;
        __syncthreads();
        ts[t] += x;
        __syncthreads();
    }
    int base = (b == 0) ? 0 : ts[b - 1];
    int end  = ts[b];
    if (b == 0 && t == 0) qoff[4 * NN] = NE;
    __syncthreads();                          // done with ts; reuse below
#pragma unroll
    for (int j = 0; j < 8; j++) cnt[t * 8 + j] = 0;
    __syncthreads();
    for (int e = base + t; e < end; e += 256) {
        int v = pk[e];
        atomicAdd(&cnt[((v & 511) << 2) | src_quad(v >> 9)], 1);
    }
    __syncthreads();
    int c8[8];
    int p = 0;
#pragma unroll
    for (int j = 0; j < 8; j++) { c8[j] = cnt[t * 8 + j]; p += c8[j]; }
    ts[t] = p;
    __syncthreads();
    for (int off = 1; off < 256; off <<= 1) {
        int x = (t >= off) ? ts[t - off] : 0;
        __syncthreads();
        ts[t] += x;
        __syncthreads();
    }
    int run = ts[t] - p;
#pragma unroll
    for (int j = 0; j < 8; j++) {
        int ci = t * 8 + j;
        cnt[ci] = run;
        int n0 = b * 512 + (ci >> 2);
        if (n0 < NN) qoff[n0 * 4 + (ci & 3)] = base + run;
        run += c8[j];
    }
    __syncthreads();
    for (int e = base + t; e < end; e += 256) {
        int v = pk[e];
        int src = v >> 9;
        int pos = atomicAdd(&cnt[((v & 511) << 2) | src_quad(src)], 1);
        stage[pos] = src;
    }
    __syncthreads();
    int sz = end - base;
    for (int i = t; i < sz; i += 256) pk[base + i] = stage[i];
}

// ---------- aggregate + t1; BN1 stats. 32 nodes/block, grid 3125 ----------
__global__ void __launch_bounds__(256) k_A(const float4* __restrict__ P4,
                                           const int* __restrict__ csr,
                                           const int* __restrict__ qoff,
                                           const float* __restrict__ eps,
                                           const float* __restrict__ b1, int l,
                                           float4* __restrict__ T4,
                                           float* __restrict__ gs) {
    __shared__ float ls[64];
    int t = threadIdx.x;
    if (t < 64) ls[t] = 0.f;
    __syncthreads();
    int g = t >> 3, i = t & 7;
    int n = blockIdx.x * 32 + g;
    float e1 = 1.f + eps[l];
    int e0 = qoff[4 * n], eend = qoff[4 * n + 4];
    float4 p = P4[(size_t)n * 8 + i];
    float4 acc;
    acc.x = e1 * p.x; acc.y = e1 * p.y; acc.z = e1 * p.z; acc.w = e1 * p.w;
    int e = e0;
    for (; e + 8 <= eend; e += 8) {
        int s0 = csr[e], s1 = csr[e + 1], s2 = csr[e + 2], s3 = csr[e + 3];
        int s4 = csr[e + 4], s5 = csr[e + 5], s6 = csr[e + 6], s7 = csr[e + 7];
        float4 q0 = P4[(size_t)s0 * 8 + i];
        float4 q1 = P4[(size_t)s1 * 8 + i];
        float4 q2 = P4[(size_t)s2 * 8 + i];
        float4 q3 = P4[(size_t)s3 * 8 + i];
        float4 q4 = P4[(size_t)s4 * 8 + i];
        float4 q5 = P4[(size_t)s5 * 8 + i];
        float4 q6 = P4[(size_t)s6 * 8 + i];
        float4 q7 = P4[(size_t)s7 * 8 + i];
        acc.x += ((q0.x + q1.x) + (q2.x + q3.x)) + ((q4.x + q5.x) + (q6.x + q7.x));
        acc.y += ((q0.y + q1.y) + (q2.y + q3.y)) + ((q4.y + q5.y) + (q6.y + q7.y));
        acc.z += ((q0.z + q1.z) + (q2.z + q3.z)) + ((q4.z + q5.z) + (q6.z + q7.z));
        acc.w += ((q0.w + q1.w) + (q2.w + q3.w)) + ((q4.w + q5.w) + (q6.w + q7.w));
    }
    for (; e + 4 <= eend; e += 4) {
        int s0 = csr[e], s1 = csr[e + 1], s2 = csr[e + 2], s3 = csr[e + 3];
        float4 q0 = P4[(size_t)s0 * 8 + i];
        float4 q1 = P4[(size_t)s1 * 8 + i];
        float4 q2 = P4[(size_t)s2 * 8 + i];
        float4 q3 = P4[(size_t)s3 * 8 + i];
        acc.x += (q0.x + q1.x) + (q2.x + q3.x);
        acc.y += (q0.y + q1.y) + (q2.y + q3.y);
        acc.z += (q0.z + q1.z) + (q2.z + q3.z);
        acc.w += (q0.w + q1.w) + (q2.w + q3.w);
    }
    for (; e < eend; e++) {
        int s = csr[e];
        float4 q = P4[(size_t)s * 8 + i];
        acc.x += q.x; acc.y += q.y; acc.z += q.z; acc.w += q.w;
    }
    float4 bb = ((const float4*)(b1 + l * 32))[i];
    acc.x += bb.x; acc.y += bb.y; acc.z += bb.z; acc.w += bb.w;
    T4[(size_t)n * 8 + i] = acc;
    float sx = acc.x, sy = acc.y, sz = acc.z, sw = acc.w;
    float qx = acc.x * acc.x, qy = acc.y * acc.y, qz = acc.z * acc.z, qw = acc.w * acc.w;
#pragma unroll
    for (int off = 8; off < 64; off <<= 1) {
        sx += __shfl_xor(sx, off); sy += __shfl_xor(sy, off);
        sz += __shfl_xor(sz, off); sw += __shfl_xor(sw, off);
        qx += __shfl_xor(qx, off); qy += __shfl_xor(qy, off);
        qz += __shfl_xor(qz, off); qw += __shfl_xor(qw, off);
    }
    if ((t & 56) == 0) {
        atomicAdd(&ls[4 * i + 0], sx); atomicAdd(&ls[4 * i + 1], sy);
        atomicAdd(&ls[4 * i + 2], sz); atomicAdd(&ls[4 * i + 3], sw);
        atomicAdd(&ls[32 + 4 * i + 0], qx); atomicAdd(&ls[32 + 4 * i + 1], qy);
        atomicAdd(&ls[32 + 4 * i + 2], qz); atomicAdd(&ls[32 + 4 * i + 3], qw);
    }
    __syncthreads();
    if (t < 64) atomicAdd(&gs[(blockIdx.x & 7) * 64 + t], ls[t]);
}

// ---------- t2 = relu(bn1(t1)) @ W2^T + b2; BN2 stats. 128 nodes/block, grid 782 ----------
__global__ void __launch_bounds__(256) k_D(float4* __restrict__ T4,
                                           const float4* __restrict__ W2T4,
                                           const float* __restrict__ b2,
                                           const float* __restrict__ g1,
                                           const float* __restrict__ bt1, int l,
                                           float* __restrict__ gs) {
    __shared__ float sc[32], sh[32], ls[64], a1s[128 * 33];
    int t = threadIdx.x, blk = blockIdx.x;
    if (t < 32) {
        float s0 = 0.f, s1 = 0.f;
#pragma unroll
        for (int r = 0; r < 8; r++) { s0 += gs[r * 64 + t]; s1 += gs[r * 64 + 32 + t]; }
        float m = s0 * (1.f / NN);
        float var = s1 * (1.f / NN) - m * m;
        float s = g1[l * 32 + t] * rsqrtf(var + 1e-5f);
        sc[t] = s; sh[t] = bt1[l * 32 + t] - m * s;
    } else if (t >= 64 && t < 128) {
        ls[t - 64] = 0.f;
    }
    __syncthreads();
    int nbase = blk * 128;
#pragma unroll
    for (int q = 0; q < 4; q++) {
        int idx = t + 256 * q;
        int nd = idx >> 3, c4 = idx & 7;
        int node = nbase + nd;
        if (node > NN - 1) node = NN - 1;
        float4 x = T4[(size_t)node * 8 + c4];
        float* dst = a1s + nd * 33 + 4 * c4;
        dst[0] = fmaxf(x.x * sc[4 * c4 + 0] + sh[4 * c4 + 0], 0.f);
        dst[1] = fmaxf(x.y * sc[4 * c4 + 1] + sh[4 * c4 + 1], 0.f);
        dst[2] = fmaxf(x.z * sc[4 * c4 + 2] + sh[4 * c4 + 2], 0.f);
        dst[3] = fmaxf(x.w * sc[4 * c4 + 3] + sh[4 * c4 + 3], 0.f);
    }
    __syncthreads();
    int i = t & 7, g = t >> 3;
    const float4* b24 = (const float4*)(b2 + l * 32);
    float4 b = b24[i];
    float4 acc[4];
#pragma unroll
    for (int j = 0; j < 4; j++) acc[j] = b;
    const float* xr0 = a1s + (g * 4) * 33;
#pragma unroll
    for (int k = 0; k < 32; k++) {
        float4 w = W2T4[k * 8 + i];
        float x0 = xr0[k], x1 = xr0[33 + k], x2 = xr0[66 + k], x3 = xr0[99 + k];
        acc[0].x += x0 * w.x; acc[0].y += x0 * w.y; acc[0].z += x0 * w.z; acc[0].w += x0 * w.w;
        acc[1].x += x1 * w.x; acc[1].y += x1 * w.y; acc[1].z += x1 * w.z; acc[1].w += x1 * w.w;
        acc[2].x += x2 * w.x; acc[2].y += x2 * w.y; acc[2].z += x2 * w.z; acc[2].w += x2 * w.w;
        acc[3].x += x3 * w.x; acc[3].y += x3 * w.y; acc[3].z += x3 * w.z; acc[3].w += x3 * w.w;
    }
    int node = nbase + g * 4;
    float sx = 0.f, sy = 0.f, sz = 0.f, sw = 0.f;
    float qx = 0.f, qy = 0.f, qz = 0.f, qw = 0.f;
#pragma unroll
    for (int j = 0; j < 4; j++) {
        if (node + j < NN) {
            T4[(size_t)(node + j) * 8 + i] = acc[j];
            sx += acc[j].x; sy += acc[j].y; sz += acc[j].z; sw += acc[j].w;
            qx += acc[j].x * acc[j].x; qy += acc[j].y * acc[j].y;
            qz += acc[j].z * acc[j].z; qw += acc[j].w * acc[j].w;
        }
    }
#pragma unroll
    for (int off = 8; off < 64; off <<= 1) {
        sx += __shfl_xor(sx, off); sy += __shfl_xor(sy, off);
        sz += __shfl_xor(sz, off); sw += __shfl_xor(sw, off);
        qx += __shfl_xor(qx, off); qy += __shfl_xor(qy, off);
        qz += __shfl_xor(qz, off); qw += __shfl_xor(qw, off);
    }
    if ((t & 56) == 0) {
        atomicAdd(&ls[4 * i + 0], sx); atomicAdd(&ls[4 * i + 1], sy);
        atomicAdd(&ls[4 * i + 2], sz); atomicAdd(&ls[4 * i + 3], sw);
        atomicAdd(&ls[32 + 4 * i + 0], qx); atomicAdd(&ls[32 + 4 * i + 1], qy);
        atomicAdd(&ls[32 + 4 * i + 2], qz); atomicAdd(&ls[32 + 4 * i + 3], qw);
    }
    __syncthreads();
    if (t < 64) atomicAdd(&gs[512 + (blk & 7) * 64 + t], ls[t]);
}

// ---------- l<3: P = M·relu(bn2(t2)) + c. 128 nodes/block, grid 782 ----------
__global__ void __launch_bounds__(256) k_Fm(const float4* __restrict__ T4,
                                            const float* __restrict__ g2,
                                            const float* __restrict__ bt2, int l,
                                            const float* __restrict__ gs,
                                            const float4* __restrict__ MT4,
                                            const float* __restrict__ C,
                                            float4* __restrict__ P4) {
    __shared__ float sc[32], sh[32], a2s[128 * 33];
    int t = threadIdx.x, blk = blockIdx.x;
    if (t < 32) {
        float s0 = 0.f, s1 = 0.f;
#pragma unroll
        for (int r = 0; r < 8; r++) { s0 += gs[512 + r * 64 + t]; s1 += gs[512 + r * 64 + 32 + t]; }
        float m = s0 * (1.f / NN);
        float var = s1 * (1.f / NN) - m * m;
        float s = g2[l * 32 + t] * rsqrtf(var + 1e-5f);
        sc[t] = s; sh[t] = bt2[l * 32 + t] - m * s;
    }
    __syncthreads();
    int nbase = blk * 128;
#pragma unroll
    for (int q = 0; q < 4; q++) {
        int idx = t + 256 * q;
        int nd = idx >> 3, c4 = idx & 7;
        int node = nbase + nd;
        if (node > NN - 1) node = NN - 1;
        float4 x = T4[(size_t)node * 8 + c4];
        float* dst = a2s + nd * 33 + 4 * c4;
        dst[0] = fmaxf(x.x * sc[4 * c4 + 0] + sh[4 * c4 + 0], 0.f);
        dst[1] = fmaxf(x.y * sc[4 * c4 + 1] + sh[4 * c4 + 1], 0.f);
        dst[2] = fmaxf(x.z * sc[4 * c4 + 2] + sh[4 * c4 + 2], 0.f);
        dst[3] = fmaxf(x.w * sc[4 * c4 + 3] + sh[4 * c4 + 3], 0.f);
    }
    __syncthreads();
    int i = t & 7, g = t >> 3;
    const float4* C4 = (const float4*)(C + l * 32);
    float4 c0 = C4[i];
    float4 acc[4];
#pragma unroll
    for (int j = 0; j < 4; j++) acc[j] = c0;
    const float* xr0 = a2s + (g * 4) * 33;
    const float4* Mt = MT4 + l * 256;
#pragma unroll
    for (int k = 0; k < 32; k++) {
        float4 w = Mt[k * 8 + i];
        float x0 = xr0[k], x1 = xr0[33 + k], x2 = xr0[66 + k], x3 = xr0[99 + k];
        acc[0].x += x0 * w.x; acc[0].y += x0 * w.y; acc[0].z += x0 * w.z; acc[0].w += x0 * w.w;
        acc[1].x += x1 * w.x; acc[1].y += x1 * w.y; acc[1].z += x1 * w.z; acc[1].w += x1 * w.w;
        acc[2].x += x2 * w.x; acc[2].y += x2 * w.y; acc[2].z += x2 * w.z; acc[2].w += x2 * w.w;
        acc[3].x += x3 * w.x; acc[3].y += x3 * w.y; acc[3].z += x3 * w.z; acc[3].w += x3 * w.w;
    }
    int node = nbase + g * 4;
#pragma unroll
    for (int j = 0; j < 4; j++)
        if (node + j < NN) P4[(size_t)(node + j) * 8 + i] = acc[j];
}

// ---------- l==3: out = W3·relu(bn2(t2)) + b3. 32 nodes/block, grid 3125 ----------
__global__ void __launch_bounds__(256) k_F3(const float4* __restrict__ T4,
                                            const float* __restrict__ g2,
                                            const float* __restrict__ bt2,
                                            const float* __restrict__ gs,
                                            const float4* __restrict__ W3T4,
                                            const float* __restrict__ b3,
                                            float4* __restrict__ out4) {
    __shared__ float sc[32], sh[32], a2s[32 * 33];
    int t = threadIdx.x, blk = blockIdx.x;
    if (t < 32) {
        float s0 = 0.f, s1 = 0.f;
#pragma unroll
        for (int r = 0; r < 8; r++) { s0 += gs[512 + r * 64 + t]; s1 += gs[512 + r * 64 + 32 + t]; }
        float m = s0 * (1.f / NN);
        float var = s1 * (1.f / NN) - m * m;
        float s = g2[3 * 32 + t] * rsqrtf(var + 1e-5f);
        sc[t] = s; sh[t] = bt2[3 * 32 + t] - m * s;
    }
    __syncthreads();
    {
        int nd = t >> 3, c4 = t & 7;
        float4 x = T4[(size_t)(blk * 32 + nd) * 8 + c4];
        float* dst = a2s + nd * 33 + 4 * c4;
        dst[0] = fmaxf(x.x * sc[4 * c4 + 0] + sh[4 * c4 + 0], 0.f);
        dst[1] = fmaxf(x.y * sc[4 * c4 + 1] + sh[4 * c4 + 1], 0.f);
        dst[2] = fmaxf(x.z * sc[4 * c4 + 2] + sh[4 * c4 + 2], 0.f);
        dst[3] = fmaxf(x.w * sc[4 * c4 + 3] + sh[4 * c4 + 3], 0.f);
    }
    __syncthreads();
    int j = t & 31, g = t >> 5;
    const float4* b34 = (const float4*)(b3 + 3 * 128);
    float4 b = b34[j];
    float4 acc[4];
#pragma unroll
    for (int jj = 0; jj < 4; jj++) acc[jj] = b;
    const float* xr0 = a2s + (g * 4) * 33;
#pragma unroll
    for (int k = 0; k < 32; k++) {
        float4 w = W3T4[k * 32 + j];
        float x0 = xr0[k], x1 = xr0[33 + k], x2 = xr0[66 + k], x3 = xr0[99 + k];
        acc[0].x += x0 * w.x; acc[0].y += x0 * w.y; acc[0].z += x0 * w.z; acc[0].w += x0 * w.w;
        acc[1].x += x1 * w.x; acc[1].y += x1 * w.y; acc[1].z += x1 * w.z; acc[1].w += x1 * w.w;
        acc[2].x += x2 * w.x; acc[2].y += x2 * w.y; acc[2].z += x2 * w.z; acc[2].w += x2 * w.w;
        acc[3].x += x3 * w.x; acc[3].y += x3 * w.y; acc[3].z += x3 * w.z; acc[3].w += x3 * w.w;
    }
    size_t node = (size_t)blk * 32 + g * 4;
#pragma unroll
    for (int jj = 0; jj < 4; jj++)
        out4[(node + jj) * 32 + j] = acc[jj];
}

extern "C" void kernel_launch(void* const* d_in, const int* in_sizes, int n_in,
                              void* d_out, int out_size, void* d_ws, size_t ws_size,
                              hipStream_t stream) {
    const float* X   = (const float*)d_in[0];
    const int*   EI  = (const int*)d_in[1];
    const float* eps = (const float*)d_in[2];
    const float* W1  = (const float*)d_in[3];
    const float* b1  = (const float*)d_in[4];
    const float* g1  = (const float*)d_in[5];
    const float* bt1 = (const float*)d_in[6];
    const float* W2  = (const float*)d_in[7];
    const float* b2  = (const float*)d_in[8];
    const float* g2  = (const float*)d_in[9];
    const float* bt2 = (const float*)d_in[10];
    const float* W3  = (const float*)d_in[11];
    const float* b3  = (const float*)d_in[12];

    char* ws = (char*)d_ws;
    float* P       = (float*)(ws + OFF_P);
    float* T       = (float*)(ws + OFF_T);
    int*   pk      = (int*)(ws + OFF_PK);
    int*   qoff    = (int*)(ws + OFF_QOFF);
    int*   counts  = (int*)(ws + OFF_COUNTS);
    float* stats   = (float*)(ws + OFF_STATS);
    float* W2T     = (float*)(ws + OFF_W2T);
    float* MT      = (float*)(ws + OFF_MT);
    float* C       = (float*)(ws + OFF_C);
    float* W3T     = (float*)(ws + OFF_W3T);

    k_init<<<SB + 15 + 782, 256, 0, stream>>>(EI, counts, W1, W2, W3, b3,
                                              W2T, MT, C, W3T, stats,
                                              (const float4*)X, (float4*)P);
    k_scatter<<<SB, 256, 0, stream>>>(EI, counts, pk);
    k_bucket<<<NB, 256, 0, stream>>>(pk, counts, qoff);

    for (int l = 0; l < 4; l++) {
        float* gs = stats + l * 1024;
        k_A<<<NN / 32, 256, 0, stream>>>((const float4*)P, pk, qoff, eps, b1, l,
                                         (float4*)T, gs);
        k_D<<<782, 256, 0, stream>>>((float4*)T,
                                     (const float4*)(W2T + (size_t)l * 1024),
                                     b2, g1, bt1, l, gs);
        if (l < 3)
            k_Fm<<<782, 256, 0, stream>>>((const float4*)T, g2, bt2, l, gs,
                                          (const float4*)MT, C, (float4*)P);
        else
            k_F3<<<3125, 256, 0, stream>>>((const float4*)T, g2, bt2, gs,
                                           (const float4*)W3T, b3, (float4*)d_out);
    }
}

// Round 16
// 436.925 us; speedup vs baseline: 6.1861x; 1.0954x over previous
//
#include <hip/hip_runtime.h>

#define NN 100000
#define NE 1600000
#define DD 128
#define HH 32
#define NB 196        // dst buckets of 512 nodes
#define SB 256        // scatter blocks
#define EPB 6250      // edges per scatter block (SB*EPB == NE)
#define BCAP 12288    // bucket capacity for LDS stage
#define QS 25000      // src quadrant size (sub-order within rows for L2 locality)

// ---- workspace layout (bytes) ----
#define OFF_P        0UL          // bf16 P: 100000*32*2 = 6.4 MB (slot kept at 12.8)
#define OFF_T        12800000UL
#define OFF_PK       25600000UL
#define OFF_QOFF     32000000UL   // (4*NN+1) ints
#define OFF_COUNTS   33600128UL
#define OFF_POFS     33800832UL
#define OFF_BTOT     34001536UL
#define OFF_BBASE    34002560UL
#define OFF_STATS    34003584UL
#define OFF_W1T      34019968UL
#define OFF_W2T      34036352UL
#define OFF_MT       34052736UL
#define OFF_C        34065024UL
#define OFF_W3T      34065536UL

__device__ __forceinline__ int src_quad(int s) {
    return (s >= 2 * QS) ? ((s >= 3 * QS) ? 3 : 2) : ((s >= QS) ? 1 : 0);
}

// bf16 helpers (RNE pack; accumulate in fp32 — only stored P is quantized)
__device__ __forceinline__ float bf2f(unsigned short u) {
    return __uint_as_float(((unsigned int)u) << 16);
}
__device__ __forceinline__ unsigned short f2bf(float f) {
    unsigned int b = __float_as_uint(f);
    return (unsigned short)((b + 0x7FFFu + ((b >> 16) & 1u)) >> 16);
}
__device__ __forceinline__ void addbf(float4& a, ushort4 q) {
    a.x += bf2f(q.x); a.y += bf2f(q.y); a.z += bf2f(q.z); a.w += bf2f(q.w);
}

// ---------- merged: binning count (blocks 0..255) + weight prep (256..271) ----------
__global__ void __launch_bounds__(256) k_init(const int* __restrict__ ei,
                                              int* __restrict__ counts,
                                              const float* __restrict__ W1,
                                              const float* __restrict__ W2,
                                              const float* __restrict__ W3,
                                              const float* __restrict__ b3,
                                              float* __restrict__ W1T,
                                              float* __restrict__ W2T,
                                              float* __restrict__ MT,
                                              float* __restrict__ C,
                                              float* __restrict__ W3T) {
    int t = threadIdx.x;
    if (blockIdx.x < SB) {
        __shared__ int c[NB];
        if (t < NB) c[t] = 0;
        __syncthreads();
        int s = blockIdx.x * EPB;
        for (int e = s + t; e < s + EPB; e += 256)
            atomicAdd(&c[ei[NE + e] >> 9], 1);
        __syncthreads();
        if (t < NB) counts[t * SB + blockIdx.x] = c[t];
        return;
    }
    int b = blockIdx.x - SB;
    if (b < 12) {
        int d = b * 256 + t;                 // 0..3071
        int l = d >> 10, rem = d & 1023;
        int i = rem >> 5, j = rem & 31;
        const float* w1r = W1 + (l + 1) * HH * DD + i * DD;
        const float* w3c = W3 + l * DD * HH + j;
        float m = 0.f;
#pragma unroll 8
        for (int k = 0; k < DD; k++) m += w1r[k] * w3c[k * HH];
        MT[l * 1024 + j * 32 + i] = m;
    } else if (b == 12) {
        for (int idx = t; idx < 4096; idx += 256) {
            int jj = idx >> 7, kk = idx & 127;
            W1T[kk * 32 + jj] = W1[jj * 128 + kk];
        }
    } else if (b == 13) {
        for (int idx = t; idx < 4096; idx += 256) {
            int l = idx >> 10, rem = idx & 1023;
            int i = rem >> 5, j = rem & 31;
            W2T[l * 1024 + j * 32 + i] = W2[l * 1024 + i * 32 + j];
        }
    } else if (b == 14) {
        for (int idx = t; idx < 4096; idx += 256) {
            int jj = idx >> 5, kk = idx & 31;
            W3T[kk * 128 + jj] = W3[3 * 4096 + jj * 32 + kk];
        }
    } else {
        if (t < 96) {
            int l = t >> 5, ii = t & 31;
            const float* w1r = W1 + (l + 1) * HH * DD + ii * DD;
            const float* bb = b3 + l * DD;
            float c = 0.f;
#pragma unroll 8
            for (int k = 0; k < DD; k++) c += w1r[k] * bb[k];
            C[l * 32 + ii] = c;
        }
    }
}

__global__ void __launch_bounds__(256) k_scanX(const int* __restrict__ counts,
                                               int* __restrict__ pofs,
                                               int* __restrict__ btot) {
    __shared__ int s[256];
    int t = threadIdx.x, b = blockIdx.x;
    int v = counts[b * SB + t];
    s[t] = v;
    __syncthreads();
    for (int off = 1; off < 256; off <<= 1) {
        int x = (t >= off) ? s[t - off] : 0;
        __syncthreads();
        s[t] += x;
        __syncthreads();
    }
    pofs[b * SB + t] = s[t] - v;
    if (t == 255) btot[b] = s[255];
}

__global__ void __launch_bounds__(256) k_scanY(const int* __restrict__ btot,
                                               int* __restrict__ bbase,
                                               int* __restrict__ qoff) {
    __shared__ int s[256];
    int t = threadIdx.x;
    int v = (t < NB) ? btot[t] : 0;
    s[t] = v;
    __syncthreads();
    for (int off = 1; off < 256; off <<= 1) {
        int x = (t >= off) ? s[t - off] : 0;
        __syncthreads();
        s[t] += x;
        __syncthreads();
    }
    if (t < NB) bbase[t] = s[t] - v;
    if (t == NB - 1) bbase[NB] = s[t];
    if (t == 0) qoff[4 * NN] = NE;
}

__global__ void __launch_bounds__(256) k_scatter(const int* __restrict__ ei,
                                                 const int* __restrict__ pofs,
                                                 const int* __restrict__ bbase,
                                                 int* __restrict__ pk) {
    __shared__ int cur[NB];
    int t = threadIdx.x, blk = blockIdx.x;
    if (t < NB) cur[t] = bbase[t] + pofs[t * SB + blk];
    __syncthreads();
    int s = blk * EPB;
    for (int e = s + t; e < s + EPB; e += 256) {
        int src = ei[e], dst = ei[NE + e];
        int b = dst >> 9;
        int pos = atomicAdd(&cur[b], 1);
        pk[pos] = (src << 9) | (dst & 511);
    }
}

// ---------- bucket sort: key = (dst&511)*4 + src_quadrant; emits qoff CSR ----------
__global__ void __launch_bounds__(256) k_bucket(int* pk,
                                                const int* __restrict__ bbase,
                                                int* __restrict__ qoff) {
    __shared__ int cnt[2048];
    __shared__ int ts[256];
    __shared__ int stage[BCAP];
    int t = threadIdx.x, b = blockIdx.x;
    int base = bbase[b], end = bbase[b + 1];
#pragma unroll
    for (int j = 0; j < 8; j++) cnt[t * 8 + j] = 0;
    __syncthreads();
    for (int e = base + t; e < end; e += 256) {
        int v = pk[e];
        atomicAdd(&cnt[((v & 511) << 2) | src_quad(v >> 9)], 1);
    }
    __syncthreads();
    int c8[8];
    int p = 0;
#pragma unroll
    for (int j = 0; j < 8; j++) { c8[j] = cnt[t * 8 + j]; p += c8[j]; }
    ts[t] = p;
    __syncthreads();
    for (int off = 1; off < 256; off <<= 1) {
        int x = (t >= off) ? ts[t - off] : 0;
        __syncthreads();
        ts[t] += x;
        __syncthreads();
    }
    int run = ts[t] - p;
#pragma unroll
    for (int j = 0; j < 8; j++) {
        int ci = t * 8 + j;
        cnt[ci] = run;
        int n0 = b * 512 + (ci >> 2);
        if (n0 < NN) qoff[n0 * 4 + (ci & 3)] = base + run;
        run += c8[j];
    }
    __syncthreads();
    for (int e = base + t; e < end; e += 256) {
        int v = pk[e];
        int src = v >> 9;
        int pos = atomicAdd(&cnt[((v & 511) << 2) | src_quad(src)], 1);
        stage[pos] = src;
    }
    __syncthreads();
    int sz = end - base;
    for (int i = t; i < sz; i += 256) pk[base + i] = stage[i];
}

// ---------- P = bf16(X @ W1[0]^T) : 128 nodes/block, grid 782 ----------
__global__ void __launch_bounds__(256) k_P(const float4* __restrict__ X4,
                                           const float4* __restrict__ W1T4,
                                           ushort4* __restrict__ Pb) {
    __shared__ float xs[128 * 33];
    int t = threadIdx.x, blk = blockIdx.x;
    int i = t & 7, g = t >> 3;
    int nbase = blk * 128;
    float4 acc[4];
#pragma unroll
    for (int j = 0; j < 4; j++) acc[j] = make_float4(0.f, 0.f, 0.f, 0.f);
    for (int kt = 0; kt < 4; kt++) {
        __syncthreads();
#pragma unroll
        for (int q = 0; q < 4; q++) {
            int idx = t + 256 * q;
            int nd = idx >> 3, c4 = idx & 7;
            int node = nbase + nd;
            if (node > NN - 1) node = NN - 1;
            float4 v = X4[(size_t)node * 32 + kt * 8 + c4];
            float* dst = xs + nd * 33 + 4 * c4;
            dst[0] = v.x; dst[1] = v.y; dst[2] = v.z; dst[3] = v.w;
        }
        __syncthreads();
        const float4* Wk = W1T4 + (size_t)(kt * 32) * 8 + i;
        const float* xr0 = xs + (g * 4) * 33;
#pragma unroll
        for (int k = 0; k < 32; k++) {
            float4 w = Wk[k * 8];
            float x0 = xr0[k], x1 = xr0[33 + k], x2 = xr0[66 + k], x3 = xr0[99 + k];
            acc[0].x += x0 * w.x; acc[0].y += x0 * w.y; acc[0].z += x0 * w.z; acc[0].w += x0 * w.w;
            acc[1].x += x1 * w.x; acc[1].y += x1 * w.y; acc[1].z += x1 * w.z; acc[1].w += x1 * w.w;
            acc[2].x += x2 * w.x; acc[2].y += x2 * w.y; acc[2].z += x2 * w.z; acc[2].w += x2 * w.w;
            acc[3].x += x3 * w.x; acc[3].y += x3 * w.y; acc[3].z += x3 * w.z; acc[3].w += x3 * w.w;
        }
    }
    int node = nbase + g * 4;
#pragma unroll
    for (int j = 0; j < 4; j++)
        if (node + j < NN) {
            ushort4 o;
            o.x = f2bf(acc[j].x); o.y = f2bf(acc[j].y);
            o.z = f2bf(acc[j].z); o.w = f2bf(acc[j].w);
            Pb[(size_t)(node + j) * 8 + i] = o;
        }
}

// ---------- aggregate + t1; BN1 stats. 32 nodes/block, grid 3125; bf16 P gather ----------
__global__ void __launch_bounds__(256) k_A(const ushort4* __restrict__ Pb,
                                           const int* __restrict__ csr,
                                           const int* __restrict__ qoff,
                                           const float* __restrict__ eps,
                                           const float* __restrict__ b1, int l,
                                           float4* __restrict__ T4,
                                           float* __restrict__ gs) {
    __shared__ float ls[64];
    int t = threadIdx.x;
    if (t < 64) ls[t] = 0.f;
    __syncthreads();
    int g = t >> 3, i = t & 7;
    int n = blockIdx.x * 32 + g;
    float e1 = 1.f + eps[l];
    int e0 = qoff[4 * n], eend = qoff[4 * n + 4];
    ushort4 pq = Pb[(size_t)n * 8 + i];
    float4 acc;
    acc.x = e1 * bf2f(pq.x); acc.y = e1 * bf2f(pq.y);
    acc.z = e1 * bf2f(pq.z); acc.w = e1 * bf2f(pq.w);
    int e = e0;
    for (; e + 8 <= eend; e += 8) {
        int s0 = csr[e], s1 = csr[e + 1], s2 = csr[e + 2], s3 = csr[e + 3];
        int s4 = csr[e + 4], s5 = csr[e + 5], s6 = csr[e + 6], s7 = csr[e + 7];
        ushort4 q0 = Pb[(size_t)s0 * 8 + i];
        ushort4 q1 = Pb[(size_t)s1 * 8 + i];
        ushort4 q2 = Pb[(size_t)s2 * 8 + i];
        ushort4 q3 = Pb[(size_t)s3 * 8 + i];
        ushort4 q4 = Pb[(size_t)s4 * 8 + i];
        ushort4 q5 = Pb[(size_t)s5 * 8 + i];
        ushort4 q6 = Pb[(size_t)s6 * 8 + i];
        ushort4 q7 = Pb[(size_t)s7 * 8 + i];
        addbf(acc, q0); addbf(acc, q1); addbf(acc, q2); addbf(acc, q3);
        addbf(acc, q4); addbf(acc, q5); addbf(acc, q6); addbf(acc, q7);
    }
    for (; e + 4 <= eend; e += 4) {
        int s0 = csr[e], s1 = csr[e + 1], s2 = csr[e + 2], s3 = csr[e + 3];
        ushort4 q0 = Pb[(size_t)s0 * 8 + i];
        ushort4 q1 = Pb[(size_t)s1 * 8 + i];
        ushort4 q2 = Pb[(size_t)s2 * 8 + i];
        ushort4 q3 = Pb[(size_t)s3 * 8 + i];
        addbf(acc, q0); addbf(acc, q1); addbf(acc, q2); addbf(acc, q3);
    }
    for (; e < eend; e++) {
        int s = csr[e];
        ushort4 q = Pb[(size_t)s * 8 + i];
        addbf(acc, q);
    }
    float4 bb = ((const float4*)(b1 + l * 32))[i];
    acc.x += bb.x; acc.y += bb.y; acc.z += bb.z; acc.w += bb.w;
    T4[(size_t)n * 8 + i] = acc;
    float sx = acc.x, sy = acc.y, sz = acc.z, sw = acc.w;
    float qx = acc.x * acc.x, qy = acc.y * acc.y, qz = acc.z * acc.z, qw = acc.w * acc.w;
#pragma unroll
    for (int off = 8; off < 64; off <<= 1) {
        sx += __shfl_xor(sx, off); sy += __shfl_xor(sy, off);
        sz += __shfl_xor(sz, off); sw += __shfl_xor(sw, off);
        qx += __shfl_xor(qx, off); qy += __shfl_xor(qy, off);
        qz += __shfl_xor(qz, off); qw += __shfl_xor(qw, off);
    }
    if ((t & 56) == 0) {
        atomicAdd(&ls[4 * i + 0], sx); atomicAdd(&ls[4 * i + 1], sy);
        atomicAdd(&ls[4 * i + 2], sz); atomicAdd(&ls[4 * i + 3], sw);
        atomicAdd(&ls[32 + 4 * i + 0], qx); atomicAdd(&ls[32 + 4 * i + 1], qy);
        atomicAdd(&ls[32 + 4 * i + 2], qz); atomicAdd(&ls[32 + 4 * i + 3], qw);
    }
    __syncthreads();
    if (t < 64) atomicAdd(&gs[(blockIdx.x & 7) * 64 + t], ls[t]);
}

// ---------- t2 = relu(bn1(t1)) @ W2^T + b2; BN2 stats. 128 nodes/block, grid 782 ----------
__global__ void __launch_bounds__(256) k_D(float4* __restrict__ T4,
                                           const float4* __restrict__ W2T4,
                                           const float* __restrict__ b2,
                                           const float* __restrict__ g1,
                                           const float* __restrict__ bt1, int l,
                                           float* __restrict__ gs) {
    __shared__ float sc[32], sh[32], ls[64], a1s[128 * 33];
    int t = threadIdx.x, blk = blockIdx.x;
    if (t < 32) {
        float s0 = 0.f, s1 = 0.f;
#pragma unroll
        for (int r = 0; r < 8; r++) { s0 += gs[r * 64 + t]; s1 += gs[r * 64 + 32 + t]; }
        float m = s0 * (1.f / NN);
        float var = s1 * (1.f / NN) - m * m;
        float s = g1[l * 32 + t] * rsqrtf(var + 1e-5f);
        sc[t] = s; sh[t] = bt1[l * 32 + t] - m * s;
    } else if (t >= 64 && t < 128) {
        ls[t - 64] = 0.f;
    }
    __syncthreads();
    int nbase = blk * 128;
#pragma unroll
    for (int q = 0; q < 4; q++) {
        int idx = t + 256 * q;
        int nd = idx >> 3, c4 = idx & 7;
        int node = nbase + nd;
        if (node > NN - 1) node = NN - 1;
        float4 x = T4[(size_t)node * 8 + c4];
        float* dst = a1s + nd * 33 + 4 * c4;
        dst[0] = fmaxf(x.x * sc[4 * c4 + 0] + sh[4 * c4 + 0], 0.f);
        dst[1] = fmaxf(x.y * sc[4 * c4 + 1] + sh[4 * c4 + 1], 0.f);
        dst[2] = fmaxf(x.z * sc[4 * c4 + 2] + sh[4 * c4 + 2], 0.f);
        dst[3] = fmaxf(x.w * sc[4 * c4 + 3] + sh[4 * c4 + 3], 0.f);
    }
    __syncthreads();
    int i = t & 7, g = t >> 3;
    const float4* b24 = (const float4*)(b2 + l * 32);
    float4 b = b24[i];
    float4 acc[4];
#pragma unroll
    for (int j = 0; j < 4; j++) acc[j] = b;
    const float* xr0 = a1s + (g * 4) * 33;
#pragma unroll
    for (int k = 0; k < 32; k++) {
        float4 w = W2T4[k * 8 + i];
        float x0 = xr0[k], x1 = xr0[33 + k], x2 = xr0[66 + k], x3 = xr0[99 + k];
        acc[0].x += x0 * w.x; acc[0].y += x0 * w.y; acc[0].z += x0 * w.z; acc[0].w += x0 * w.w;
        acc[1].x += x1 * w.x; acc[1].y += x1 * w.y; acc[1].z += x1 * w.z; acc[1].w += x1 * w.w;
        acc[2].x += x2 * w.x; acc[2].y += x2 * w.y; acc[2].z += x2 * w.z; acc[2].w += x2 * w.w;
        acc[3].x += x3 * w.x; acc[3].y += x3 * w.y; acc[3].z += x3 * w.z; acc[3].w += x3 * w.w;
    }
    int node = nbase + g * 4;
    float sx = 0.f, sy = 0.f, sz = 0.f, sw = 0.f;
    float qx = 0.f, qy = 0.f, qz = 0.f, qw = 0.f;
#pragma unroll
    for (int j = 0; j < 4; j++) {
        if (node + j < NN) {
            T4[(size_t)(node + j) * 8 + i] = acc[j];
            sx += acc[j].x; sy += acc[j].y; sz += acc[j].z; sw += acc[j].w;
            qx += acc[j].x * acc[j].x; qy += acc[j].y * acc[j].y;
            qz += acc[j].z * acc[j].z; qw += acc[j].w * acc[j].w;
        }
    }
#pragma unroll
    for (int off = 8; off < 64; off <<= 1) {
        sx += __shfl_xor(sx, off); sy += __shfl_xor(sy, off);
        sz += __shfl_xor(sz, off); sw += __shfl_xor(sw, off);
        qx += __shfl_xor(qx, off); qy += __shfl_xor(qy, off);
        qz += __shfl_xor(qz, off); qw += __shfl_xor(qw, off);
    }
    if ((t & 56) == 0) {
        atomicAdd(&ls[4 * i + 0], sx); atomicAdd(&ls[4 * i + 1], sy);
        atomicAdd(&ls[4 * i + 2], sz); atomicAdd(&ls[4 * i + 3], sw);
        atomicAdd(&ls[32 + 4 * i + 0], qx); atomicAdd(&ls[32 + 4 * i + 1], qy);
        atomicAdd(&ls[32 + 4 * i + 2], qz); atomicAdd(&ls[32 + 4 * i + 3], qw);
    }
    __syncthreads();
    if (t < 64) atomicAdd(&gs[512 + (blk & 7) * 64 + t], ls[t]);
}

// ---------- l<3: P = bf16(M·relu(bn2(t2)) + c). 128 nodes/block, grid 782 ----------
__global__ void __launch_bounds__(256) k_Fm(const float4* __restrict__ T4,
                                            const float* __restrict__ g2,
                                            const float* __restrict__ bt2, int l,
                                            const float* __restrict__ gs,
                                            const float4* __restrict__ MT4,
                                            const float* __restrict__ C,
                                            ushort4* __restrict__ Pb) {
    __shared__ float sc[32], sh[32], a2s[128 * 33];
    int t = threadIdx.x, blk = blockIdx.x;
    if (t < 32) {
        float s0 = 0.f, s1 = 0.f;
#pragma unroll
        for (int r = 0; r < 8; r++) { s0 += gs[512 + r * 64 + t]; s1 += gs[512 + r * 64 + 32 + t]; }
        float m = s0 * (1.f / NN);
        float var = s1 * (1.f / NN) - m * m;
        float s = g2[l * 32 + t] * rsqrtf(var + 1e-5f);
        sc[t] = s; sh[t] = bt2[l * 32 + t] - m * s;
    }
    __syncthreads();
    int nbase = blk * 128;
#pragma unroll
    for (int q = 0; q < 4; q++) {
        int idx = t + 256 * q;
        int nd = idx >> 3, c4 = idx & 7;
        int node = nbase + nd;
        if (node > NN - 1) node = NN - 1;
        float4 x = T4[(size_t)node * 8 + c4];
        float* dst = a2s + nd * 33 + 4 * c4;
        dst[0] = fmaxf(x.x * sc[4 * c4 + 0] + sh[4 * c4 + 0], 0.f);
        dst[1] = fmaxf(x.y * sc[4 * c4 + 1] + sh[4 * c4 + 1], 0.f);
        dst[2] = fmaxf(x.z * sc[4 * c4 + 2] + sh[4 * c4 + 2], 0.f);
        dst[3] = fmaxf(x.w * sc[4 * c4 + 3] + sh[4 * c4 + 3], 0.f);
    }
    __syncthreads();
    int i = t & 7, g = t >> 3;
    const float4* C4 = (const float4*)(C + l * 32);
    float4 c0 = C4[i];
    float4 acc[4];
#pragma unroll
    for (int j = 0; j < 4; j++) acc[j] = c0;
    const float* xr0 = a2s + (g * 4) * 33;
    const float4* Mt = MT4 + l * 256;
#pragma unroll
    for (int k = 0; k < 32; k++) {
        float4 w = Mt[k * 8 + i];
        float x0 = xr0[k], x1 = xr0[33 + k], x2 = xr0[66 + k], x3 = xr0[99 + k];
        acc[0].x += x0 * w.x; acc[0].y += x0 * w.y; acc[0].z += x0 * w.z; acc[0].w += x0 * w.w;
        acc[1].x += x1 * w.x; acc[1].y += x1 * w.y; acc[1].z += x1 * w.z; acc[1].w += x1 * w.w;
        acc[2].x += x2 * w.x; acc[2].y += x2 * w.y; acc[2].z += x2 * w.z; acc[2].w += x2 * w.w;
        acc[3].x += x3 * w.x; acc[3].y += x3 * w.y; acc[3].z += x3 * w.z; acc[3].w += x3 * w.w;
    }
    int node = nbase + g * 4;
#pragma unroll
    for (int j = 0; j < 4; j++)
        if (node + j < NN) {
            ushort4 o;
            o.x = f2bf(acc[j].x); o.y = f2bf(acc[j].y);
            o.z = f2bf(acc[j].z); o.w = f2bf(acc[j].w);
            Pb[(size_t)(node + j) * 8 + i] = o;
        }
}

// ---------- l==3: out = W3·relu(bn2(t2)) + b3. 32 nodes/block, grid 3125 ----------
__global__ void __launch_bounds__(256) k_F3(const float4* __restrict__ T4,
                                            const float* __restrict__ g2,
                                            const float* __restrict__ bt2,
                                            const float* __restrict__ gs,
                                            const float4* __restrict__ W3T4,
                                            const float* __restrict__ b3,
                                            float4* __restrict__ out4) {
    __shared__ float sc[32], sh[32], a2s[32 * 33];
    int t = threadIdx.x, blk = blockIdx.x;
    if (t < 32) {
        float s0 = 0.f, s1 = 0.f;
#pragma unroll
        for (int r = 0; r < 8; r++) { s0 += gs[512 + r * 64 + t]; s1 += gs[512 + r * 64 + 32 + t]; }
        float m = s0 * (1.f / NN);
        float var = s1 * (1.f / NN) - m * m;
        float s = g2[3 * 32 + t] * rsqrtf(var + 1e-5f);
        sc[t] = s; sh[t] = bt2[3 * 32 + t] - m * s;
    }
    __syncthreads();
    {
        int nd = t >> 3, c4 = t & 7;
        float4 x = T4[(size_t)(blk * 32 + nd) * 8 + c4];
        float* dst = a2s + nd * 33 + 4 * c4;
        dst[0] = fmaxf(x.x * sc[4 * c4 + 0] + sh[4 * c4 + 0], 0.f);
        dst[1] = fmaxf(x.y * sc[4 * c4 + 1] + sh[4 * c4 + 1], 0.f);
        dst[2] = fmaxf(x.z * sc[4 * c4 + 2] + sh[4 * c4 + 2], 0.f);
        dst[3] = fmaxf(x.w * sc[4 * c4 + 3] + sh[4 * c4 + 3], 0.f);
    }
    __syncthreads();
    int j = t & 31, g = t >> 5;
    const float4* b34 = (const float4*)(b3 + 3 * 128);
    float4 b = b34[j];
    float4 acc[4];
#pragma unroll
    for (int jj = 0; jj < 4; jj++) acc[jj] = b;
    const float* xr0 = a2s + (g * 4) * 33;
#pragma unroll
    for (int k = 0; k < 32; k++) {
        float4 w = W3T4[k * 32 + j];
        float x0 = xr0[k], x1 = xr0[33 + k], x2 = xr0[66 + k], x3 = xr0[99 + k];
        acc[0].x += x0 * w.x; acc[0].y += x0 * w.y; acc[0].z += x0 * w.z; acc[0].w += x0 * w.w;
        acc[1].x += x1 * w.x; acc[1].y += x1 * w.y; acc[1].z += x1 * w.z; acc[1].w += x1 * w.w;
        acc[2].x += x2 * w.x; acc[2].y += x2 * w.y; acc[2].z += x2 * w.z; acc[2].w += x2 * w.w;
        acc[3].x += x3 * w.x; acc[3].y += x3 * w.y; acc[3].z += x3 * w.z; acc[3].w += x3 * w.w;
    }
    size_t node = (size_t)blk * 32 + g * 4;
#pragma unroll
    for (int jj = 0; jj < 4; jj++)
        out4[(node + jj) * 32 + j] = acc[jj];
}

extern "C" void kernel_launch(void* const* d_in, const int* in_sizes, int n_in,
                              void* d_out, int out_size, void* d_ws, size_t ws_size,
                              hipStream_t stream) {
    const float* X   = (const float*)d_in[0];
    const int*   EI  = (const int*)d_in[1];
    const float* eps = (const float*)d_in[2];
    const float* W1  = (const float*)d_in[3];
    const float* b1  = (const float*)d_in[4];
    const float* g1  = (const float*)d_in[5];
    const float* bt1 = (const float*)d_in[6];
    const float* W2  = (const float*)d_in[7];
    const float* b2  = (const float*)d_in[8];
    const float* g2  = (const float*)d_in[9];
    const float* bt2 = (const float*)d_in[10];
    const float* W3  = (const float*)d_in[11];
    const float* b3  = (const float*)d_in[12];

    char* ws = (char*)d_ws;
    ushort4* Pb    = (ushort4*)(ws + OFF_P);
    float* T       = (float*)(ws + OFF_T);
    int*   pk      = (int*)(ws + OFF_PK);
    int*   qoff    = (int*)(ws + OFF_QOFF);
    int*   counts  = (int*)(ws + OFF_COUNTS);
    int*   pofs    = (int*)(ws + OFF_POFS);
    int*   btot    = (int*)(ws + OFF_BTOT);
    int*   bbase   = (int*)(ws + OFF_BBASE);
    float* stats   = (float*)(ws + OFF_STATS);
    float* W1T     = (float*)(ws + OFF_W1T);
    float* W2T     = (float*)(ws + OFF_W2T);
    float* MT      = (float*)(ws + OFF_MT);
    float* C       = (float*)(ws + OFF_C);
    float* W3T     = (float*)(ws + OFF_W3T);

    hipMemsetAsync(ws + OFF_STATS, 0, 16384, stream);

    k_init<<<SB + 16, 256, 0, stream>>>(EI, counts, W1, W2, W3, b3,
                                        W1T, W2T, MT, C, W3T);
    k_scanX<<<NB, 256, 0, stream>>>(counts, pofs, btot);
    k_scanY<<<1, 256, 0, stream>>>(btot, bbase, qoff);
    k_scatter<<<SB, 256, 0, stream>>>(EI, pofs, bbase, pk);
    k_bucket<<<NB, 256, 0, stream>>>(pk, bbase, qoff);
    k_P<<<782, 256, 0, stream>>>((const float4*)X, (const float4*)W1T, Pb);

    for (int l = 0; l < 4; l++) {
        float* gs = stats + l * 1024;
        k_A<<<NN / 32, 256, 0, stream>>>((const ushort4*)Pb, pk, qoff, eps, b1, l,
                                         (float4*)T, gs);
        k_D<<<782, 256, 0, stream>>>((float4*)T,
                                     (const float4*)(W2T + (size_t)l * 1024),
                                     b2, g1, bt1, l, gs);
        if (l < 3)
            k_Fm<<<782, 256, 0, stream>>>((const float4*)T, g2, bt2, l, gs,
                                          (const float4*)MT, C, Pb);
        else
            k_F3<<<3125, 256, 0, stream>>>((const float4*)T, g2, bt2, gs,
                                           (const float4*)W3T, b3, (float4*)d_out);
    }
}